// Round 1
// baseline (650.628 us; speedup 1.0000x reference)
//
#include <hip/hip_runtime.h>
#include <cstdint>
#include <math.h>

// ---------------------------------------------------------------------------
// Problem constants (from setup_inputs)
//   B=8
//   level 1: fine xyz1 [8,2048,3], coarse xyz2 [8,512,3], x1 [8,256,2048], x2 [8,512,512]
//   level 2: fine xyz0 [8,8192,3], coarse xyz1 [8,2048,3], x0 [8,128,8192]
//   out [8, 896, 8192] f32
// ---------------------------------------------------------------------------

// Tiled transpose: in [B, R, C] row-major -> out[b][c][r] with out row stride out_rs.
__global__ __launch_bounds__(256) void k_transpose(const float* __restrict__ in,
                                                   float* __restrict__ out,
                                                   int R, int C,
                                                   long in_bs, long out_bs, int out_rs) {
    __shared__ float tile[32][33];
    const int b = blockIdx.z;
    const int r0 = blockIdx.y * 32;
    const int c0 = blockIdx.x * 32;
    const float* inb = in + (size_t)b * in_bs;
    float* outb = out + (size_t)b * out_bs;
    const int tx = threadIdx.x;   // 0..31
    const int ty = threadIdx.y;   // 0..7
#pragma unroll
    for (int i = 0; i < 32; i += 8) {
        tile[ty + i][tx] = inb[(size_t)(r0 + ty + i) * C + (c0 + tx)];
    }
    __syncthreads();
#pragma unroll
    for (int i = 0; i < 32; i += 8) {
        outb[(size_t)(c0 + ty + i) * out_rs + (r0 + tx)] = tile[tx][ty + i];
    }
}

// Brute-force 3-NN + normalized inverse-distance weights.
// fine [B,N,3], coarse [B,S,3]; one thread per fine point; coarse staged in LDS.
template <int S>
__global__ __launch_bounds__(256) void k_knn(const float* __restrict__ fine,
                                             const float* __restrict__ coarse,
                                             int N,
                                             int* __restrict__ idx,
                                             float* __restrict__ wout) {
#pragma clang fp contract(off)
    __shared__ float4 lc[S];
    const int b = blockIdx.y;
    const int n = blockIdx.x * 256 + threadIdx.x;
    const float* cb = coarse + (size_t)b * S * 3;
    for (int s = threadIdx.x; s < S; s += 256) {
        float x = cb[3 * s], y = cb[3 * s + 1], z = cb[3 * s + 2];
        lc[s] = make_float4(x, y, z, (x * x + y * y) + z * z);
    }
    __syncthreads();
    const float* fp = fine + ((size_t)b * N + n) * 3;
    const float px = fp[0], py = fp[1], pz = fp[2];
    const float psq = (px * px + py * py) + pz * pz;
    float d0 = 1e30f, d1 = 1e30f, d2 = 1e30f;
    int i0 = 0, i1 = 0, i2 = 0;
    for (int s = 0; s < S; ++s) {
        float4 c = lc[s];
        float dot = (px * c.x + py * c.y) + pz * c.z;
        float d = (psq + c.w) - 2.0f * dot;       // same expanded form as reference
        if (d < d0)      { d2 = d1; i2 = i1; d1 = d0; i1 = i0; d0 = d; i0 = s; }
        else if (d < d1) { d2 = d1; i2 = i1; d1 = d;  i1 = s; }
        else if (d < d2) { d2 = d;  i2 = s; }
    }
    const float w0 = 1.0f / (d0 + 1e-8f);
    const float w1 = 1.0f / (d1 + 1e-8f);
    const float w2 = 1.0f / (d2 + 1e-8f);
    const float wsum = (w0 + w1) + w2;
    const size_t p = ((size_t)b * N + n) * 3;
    idx[p] = i0; idx[p + 1] = i1; idx[p + 2] = i2;
    wout[p] = w0 / wsum; wout[p + 1] = w1 / wsum; wout[p + 2] = w2 / wsum;
}

// Level-1 interpolation: gather rows of pts [8,512,512] -> inter[b][n][256+c],
// natural [B,N,C] layout (coalesced). Also per-block double partial sums.
__global__ __launch_bounds__(256) void k_interp1(const float* __restrict__ pts,
                                                 const int* __restrict__ idx,
                                                 const float* __restrict__ w,
                                                 float* __restrict__ inter,
                                                 double* __restrict__ partials) {
    const int b = blockIdx.y, n = blockIdx.x;
    const size_t p = (size_t)b * 2048 + n;
    const int i0 = idx[p * 3], i1 = idx[p * 3 + 1], i2 = idx[p * 3 + 2];
    const float w0 = w[p * 3], w1 = w[p * 3 + 1], w2 = w[p * 3 + 2];
    const float* pb = pts + (size_t)b * 512 * 512;
    const float* r0 = pb + (size_t)i0 * 512;
    const float* r1 = pb + (size_t)i1 * 512;
    const float* r2 = pb + (size_t)i2 * 512;
    float* outp = inter + p * 768 + 256;
    double ls = 0.0, lq = 0.0;
#pragma unroll
    for (int cc = 0; cc < 2; ++cc) {
        int c = threadIdx.x + cc * 256;
        float v = (w0 * r0[c] + w1 * r1[c]) + w2 * r2[c];
        outp[c] = v;
        ls += v; lq += (double)v * v;
    }
    __shared__ double sa[256], sb[256];
    const int t = threadIdx.x;
    sa[t] = ls; sb[t] = lq; __syncthreads();
    for (int s = 128; s > 0; s >>= 1) {
        if (t < s) { sa[t] += sa[t + s]; sb[t] += sb[t + s]; }
        __syncthreads();
    }
    if (t == 0) { partials[2 * p] = sa[0]; partials[2 * p + 1] = sb[0]; }
}

// Level-2 interpolation: gather rows of inter [8,2048,768], write TRANSPOSED
// into out[b][128+c][n] via a 32(n) x 64(c) LDS tile. Per-block double partials.
__global__ __launch_bounds__(256) void k_interp2(const float* __restrict__ pts,
                                                 const int* __restrict__ idx,
                                                 const float* __restrict__ w,
                                                 float* __restrict__ out,
                                                 double* __restrict__ partials) {
    __shared__ float tile[32][65];
    __shared__ int   si[32][3];
    __shared__ float sw[32][3];
    const int b = blockIdx.z, nt = blockIdx.y, cc = blockIdx.x;
    const int n0 = nt * 32, c0 = cc * 64;
    const int tid = threadIdx.x;
    if (tid < 32) {
        size_t p = ((size_t)b * 8192 + n0 + tid) * 3;
        si[tid][0] = idx[p]; si[tid][1] = idx[p + 1]; si[tid][2] = idx[p + 2];
        sw[tid][0] = w[p];   sw[tid][1] = w[p + 1];   sw[tid][2] = w[p + 2];
    }
    __syncthreads();
    const float* pb = pts + (size_t)b * 2048 * 768 + c0;
    const int cl = tid & 63;
    const int nl0 = tid >> 6;   // 0..3
    double ls = 0.0, lq = 0.0;
#pragma unroll
    for (int pass = 0; pass < 8; ++pass) {
        int nl = pass * 4 + nl0;
        float v = (sw[nl][0] * pb[(size_t)si[nl][0] * 768 + cl]
                 + sw[nl][1] * pb[(size_t)si[nl][1] * 768 + cl])
                 + sw[nl][2] * pb[(size_t)si[nl][2] * 768 + cl];
        tile[nl][cl] = v;
        ls += v; lq += (double)v * v;
    }
    __syncthreads();
    float* ob = out + (size_t)b * 896 * 8192 + (size_t)(128 + c0) * 8192 + n0;
    const int tn = tid & 31, tc0 = tid >> 5;  // 0..7
#pragma unroll
    for (int pass = 0; pass < 8; ++pass) {
        int tc = pass * 8 + tc0;
        ob[(size_t)tc * 8192 + tn] = tile[tn][tc];
    }
    __shared__ double sa[256], sb[256];
    sa[tid] = ls; sb[tid] = lq; __syncthreads();
    for (int s = 128; s > 0; s >>= 1) {
        if (tid < s) { sa[tid] += sa[tid + s]; sb[tid] += sb[tid + s]; }
        __syncthreads();
    }
    if (tid == 0) {
        size_t pl = ((size_t)b * gridDim.y + nt) * gridDim.x + cc;
        partials[2 * pl] = sa[0]; partials[2 * pl + 1] = sb[0];
    }
}

// Deterministic single-block reduction of partials -> stats {mean, 1/(std+1e-5)}.
__global__ __launch_bounds__(256) void k_finalize(const double* __restrict__ partials,
                                                  int P, double nelem,
                                                  float* __restrict__ stats) {
    __shared__ double sa[256], sb[256];
    double ls = 0.0, lq = 0.0;
    for (int i = threadIdx.x; i < P; i += 256) { ls += partials[2 * i]; lq += partials[2 * i + 1]; }
    const int t = threadIdx.x;
    sa[t] = ls; sb[t] = lq; __syncthreads();
    for (int s = 128; s > 0; s >>= 1) {
        if (t < s) { sa[t] += sa[t + s]; sb[t] += sb[t + s]; }
        __syncthreads();
    }
    if (t == 0) {
        double sum = sa[0], sq = sb[0];
        double m = sum / nelem;
        double var = (sq - sum * sum / nelem) / (nelem - 1.0);
        double sd = sqrt(var > 0.0 ? var : 0.0);
        stats[0] = (float)m;
        stats[1] = (float)(1.0 / (sd + 1e-5));
    }
}

// Normalize level-1 interp region in place: inter[:, :, 256:768].
__global__ __launch_bounds__(256) void k_norm1(float* __restrict__ inter,
                                               const float* __restrict__ stats) {
    const float m = stats[0], rs = stats[1];
    const size_t i = (size_t)blockIdx.x * 256 + threadIdx.x;   // < 8*2048*512 = 2^23
    const int c = (int)(i & 511);
    const size_t t = i >> 9;
    const int n = (int)(t & 2047);
    const int b = (int)(t >> 11);
    float* p = inter + ((size_t)b * 2048 + n) * 768 + 256 + c;
    *p = (*p - m) * rs;
}

// Normalize level-2 interp region of the output in place (float4).
__global__ __launch_bounds__(256) void k_norm2(float* __restrict__ out,
                                               const float* __restrict__ stats) {
    const float m = stats[0], rs = stats[1];
    const size_t i = (size_t)blockIdx.x * 256 + threadIdx.x;   // < 8 * 1572864
    const size_t per = (size_t)768 * 8192 / 4;                 // 1572864
    const size_t b = i / per;
    const size_t off = i - b * per;
    float4* p = (float4*)(out + b * (size_t)896 * 8192 + (size_t)128 * 8192) + off;
    float4 v = *p;
    v.x = (v.x - m) * rs; v.y = (v.y - m) * rs;
    v.z = (v.z - m) * rs; v.w = (v.w - m) * rs;
    *p = v;
}

// Copy x0 [8,128,8192] into out[:, 0:128, :] (float4).
__global__ __launch_bounds__(256) void k_copy0(const float* __restrict__ x0,
                                               float* __restrict__ out) {
    const size_t i = (size_t)blockIdx.x * 256 + threadIdx.x;   // < 8*262144
    const size_t b = i >> 18;                                  // 262144 = 2^18
    const size_t off = i & (((size_t)1 << 18) - 1);
    const float4* src = (const float4*)(x0 + b * (size_t)128 * 8192);
    float4* dst = (float4*)(out + b * (size_t)896 * 8192);
    dst[off] = src[off];
}

extern "C" void kernel_launch(void* const* d_in, const int* in_sizes, int n_in,
                              void* d_out, int out_size, void* d_ws, size_t ws_size,
                              hipStream_t stream) {
    const float* xyz0 = (const float*)d_in[0];
    const float* xyz1 = (const float*)d_in[1];
    const float* xyz2 = (const float*)d_in[2];
    const float* x0   = (const float*)d_in[3];
    const float* x1   = (const float*)d_in[4];
    const float* x2   = (const float*)d_in[5];
    float* out = (float*)d_out;
    char* ws = (char*)d_ws;

    size_t off = 0;
    auto alloc = [&](size_t bytes) {
        size_t o = off;
        off = (off + bytes + 255) & ~(size_t)255;
        return o;
    };
    float*  stats    = (float*)(ws + alloc(4 * sizeof(float)));
    double* partials = (double*)(ws + alloc((size_t)24576 * 2 * sizeof(double)));
    int*    idx1     = (int*)(ws + alloc((size_t)8 * 2048 * 3 * 4));
    float*  w1       = (float*)(ws + alloc((size_t)8 * 2048 * 3 * 4));
    int*    idx2     = (int*)(ws + alloc((size_t)8 * 8192 * 3 * 4));
    float*  w2       = (float*)(ws + alloc((size_t)8 * 8192 * 3 * 4));
    float*  pts1     = (float*)(ws + alloc((size_t)8 * 512 * 512 * 4));   // x2^T  [8,512,512]
    float*  inter    = (float*)(ws + alloc((size_t)8 * 2048 * 768 * 4));  // level-1 out, [8,2048,768]

    // ---- level 1: propagate(xyz1, xyz2, x1, x2) -> inter [8,2048,768] ----
    k_transpose<<<dim3(512 / 32, 512 / 32, 8), dim3(32, 8), 0, stream>>>(
        x2, pts1, 512, 512, 512 * 512, 512 * 512, 512);
    k_transpose<<<dim3(2048 / 32, 256 / 32, 8), dim3(32, 8), 0, stream>>>(
        x1, inter, 256, 2048, 256 * 2048, 2048 * 768, 768);
    k_knn<512><<<dim3(2048 / 256, 8), 256, 0, stream>>>(xyz1, xyz2, 2048, idx1, w1);
    k_interp1<<<dim3(2048, 8), 256, 0, stream>>>(pts1, idx1, w1, inter, partials);
    k_finalize<<<1, 256, 0, stream>>>(partials, 16384, (double)8 * 2048 * 512, stats);
    k_norm1<<<(8 * 2048 * 512) / 256, 256, 0, stream>>>(inter, stats);

    // ---- level 2: propagate(xyz0, xyz1, x0, inter^T) -> out [8,896,8192] ----
    k_knn<2048><<<dim3(8192 / 256, 8), 256, 0, stream>>>(xyz0, xyz1, 8192, idx2, w2);
    k_interp2<<<dim3(12, 256, 8), 256, 0, stream>>>(inter, idx2, w2, out, partials);
    k_finalize<<<1, 256, 0, stream>>>(partials, 24576, (double)8 * 8192 * 768, stats + 2);
    k_norm2<<<(8 * 1572864) / 256, 256, 0, stream>>>(out, stats + 2);
    k_copy0<<<(8 * 262144) / 256, 256, 0, stream>>>(x0, out);
}

// Round 2
// 318.569 us; speedup vs baseline: 2.0423x; 2.0423x over previous
//
#include <hip/hip_runtime.h>
#include <cstdint>
#include <math.h>

// ---------------------------------------------------------------------------
// Problem constants (from setup_inputs)
//   B=8
//   level 1: fine xyz1 [8,2048,3], coarse xyz2 [8,512,3], x1 [8,256,2048], x2 [8,512,512]
//   level 2: fine xyz0 [8,8192,3], coarse xyz1 [8,2048,3], x0 [8,128,8192]
//   out [8, 896, 8192] f32
// ---------------------------------------------------------------------------

// Tiled transpose: in [B, R, C] row-major -> out[b][c][r] with out row stride out_rs.
__global__ __launch_bounds__(256) void k_transpose(const float* __restrict__ in,
                                                   float* __restrict__ out,
                                                   int R, int C,
                                                   long in_bs, long out_bs, int out_rs) {
    __shared__ float tile[32][33];
    const int b = blockIdx.z;
    const int r0 = blockIdx.y * 32;
    const int c0 = blockIdx.x * 32;
    const float* inb = in + (size_t)b * in_bs;
    float* outb = out + (size_t)b * out_bs;
    const int tx = threadIdx.x;   // 0..31
    const int ty = threadIdx.y;   // 0..7
#pragma unroll
    for (int i = 0; i < 32; i += 8) {
        tile[ty + i][tx] = inb[(size_t)(r0 + ty + i) * C + (c0 + tx)];
    }
    __syncthreads();
#pragma unroll
    for (int i = 0; i < 32; i += 8) {
        outb[(size_t)(c0 + ty + i) * out_rs + (r0 + tx)] = tile[tx][ty + i];
    }
}

// Chunked brute-force 3-NN: each block scans CHUNK coarse points for 256 fine
// points, writes a sorted local top-3 (d, global_s) per point per chunk.
// Branchless insertion (cndmask chain); distance form bit-matches reference:
// fmaf(-2,dot,psq+cw) == (psq+cw) - 2*dot (2*dot is exact).
template <int CHUNK>
__global__ __launch_bounds__(256) void k_knn_chunk(const float* __restrict__ fine,
                                                   const float* __restrict__ coarse,
                                                   int N, int S,
                                                   float* __restrict__ cand_d,
                                                   int* __restrict__ cand_i) {
#pragma clang fp contract(off)
    __shared__ float4 lc[CHUNK];
    const int b = blockIdx.z;
    const int chunk = blockIdx.y;
    const int nch = gridDim.y;
    const int n = blockIdx.x * 256 + threadIdx.x;
    const int s0 = chunk * CHUNK;
    const float* cb = coarse + ((size_t)b * S + s0) * 3;
    for (int s = threadIdx.x; s < CHUNK; s += 256) {
        float x = cb[3 * s], y = cb[3 * s + 1], z = cb[3 * s + 2];
        lc[s] = make_float4(x, y, z, (x * x + y * y) + z * z);
    }
    __syncthreads();
    const float* fp = fine + ((size_t)b * N + n) * 3;
    const float px = fp[0], py = fp[1], pz = fp[2];
    const float psq = (px * px + py * py) + pz * pz;
    float d0 = 1e30f, d1 = 1e30f, d2 = 1e30f;
    int i0 = 0, i1 = 0, i2 = 0;
#pragma unroll 4
    for (int s = 0; s < CHUNK; ++s) {
        float4 c = lc[s];
        float dot = (px * c.x + py * c.y) + pz * c.z;
        float d = fmaf(-2.0f, dot, psq + c.w);
        const bool lt0 = d < d0, lt1 = d < d1, lt2 = d < d2;
        d2 = lt1 ? d1 : (lt2 ? d : d2);
        i2 = lt1 ? i1 : (lt2 ? s : i2);
        d1 = lt0 ? d0 : (lt1 ? d : d1);
        i1 = lt0 ? i0 : (lt1 ? s : i1);
        d0 = lt0 ? d : d0;
        i0 = lt0 ? s : i0;
    }
    const size_t p = (((size_t)b * N + n) * nch + chunk) * 3;
    cand_d[p] = d0; cand_d[p + 1] = d1; cand_d[p + 2] = d2;
    cand_i[p] = s0 + i0; cand_i[p + 1] = s0 + i1; cand_i[p + 2] = s0 + i2;
}

// Merge per-chunk candidates (chunk-major, each chunk sorted ascending) into
// the final top-3 + normalized inverse-distance weights. Strict < keeps the
// earlier (lower-index) candidate on ties, matching top_k tie-breaking.
__global__ __launch_bounds__(256) void k_knn_merge(const float* __restrict__ cand_d,
                                                   const int* __restrict__ cand_i,
                                                   int npts, int ncand,
                                                   int* __restrict__ idx,
                                                   float* __restrict__ wout) {
    const int p = blockIdx.x * 256 + threadIdx.x;
    if (p >= npts) return;
    const float* cd = cand_d + (size_t)p * ncand;
    const int*   ci = cand_i + (size_t)p * ncand;
    float d0 = 1e30f, d1 = 1e30f, d2 = 1e30f;
    int i0 = 0, i1 = 0, i2 = 0;
    for (int k = 0; k < ncand; ++k) {
        const float d = cd[k];
        const int s = ci[k];
        const bool lt0 = d < d0, lt1 = d < d1, lt2 = d < d2;
        d2 = lt1 ? d1 : (lt2 ? d : d2);
        i2 = lt1 ? i1 : (lt2 ? s : i2);
        d1 = lt0 ? d0 : (lt1 ? d : d1);
        i1 = lt0 ? i0 : (lt1 ? s : i1);
        d0 = lt0 ? d : d0;
        i0 = lt0 ? s : i0;
    }
    const float w0 = 1.0f / (d0 + 1e-8f);
    const float w1 = 1.0f / (d1 + 1e-8f);
    const float w2 = 1.0f / (d2 + 1e-8f);
    const float wsum = (w0 + w1) + w2;
    const size_t q = (size_t)p * 3;
    idx[q] = i0; idx[q + 1] = i1; idx[q + 2] = i2;
    wout[q] = w0 / wsum; wout[q + 1] = w1 / wsum; wout[q + 2] = w2 / wsum;
}

// Level-1 interpolation: gather rows of pts [8,512,512] -> inter[b][n][256+c],
// natural [B,N,C] layout (coalesced). Also per-block double partial sums.
__global__ __launch_bounds__(256) void k_interp1(const float* __restrict__ pts,
                                                 const int* __restrict__ idx,
                                                 const float* __restrict__ w,
                                                 float* __restrict__ inter,
                                                 double* __restrict__ partials) {
    const int b = blockIdx.y, n = blockIdx.x;
    const size_t p = (size_t)b * 2048 + n;
    const int i0 = idx[p * 3], i1 = idx[p * 3 + 1], i2 = idx[p * 3 + 2];
    const float w0 = w[p * 3], w1 = w[p * 3 + 1], w2 = w[p * 3 + 2];
    const float* pb = pts + (size_t)b * 512 * 512;
    const float* r0 = pb + (size_t)i0 * 512;
    const float* r1 = pb + (size_t)i1 * 512;
    const float* r2 = pb + (size_t)i2 * 512;
    float* outp = inter + p * 768 + 256;
    double ls = 0.0, lq = 0.0;
#pragma unroll
    for (int cc = 0; cc < 2; ++cc) {
        int c = threadIdx.x + cc * 256;
        float v = (w0 * r0[c] + w1 * r1[c]) + w2 * r2[c];
        outp[c] = v;
        ls += v; lq += (double)v * v;
    }
    __shared__ double sa[256], sb[256];
    const int t = threadIdx.x;
    sa[t] = ls; sb[t] = lq; __syncthreads();
    for (int s = 128; s > 0; s >>= 1) {
        if (t < s) { sa[t] += sa[t + s]; sb[t] += sb[t + s]; }
        __syncthreads();
    }
    if (t == 0) { partials[2 * p] = sa[0]; partials[2 * p + 1] = sb[0]; }
}

// Level-2 interpolation: gather rows of inter [8,2048,768], write TRANSPOSED
// into out[b][128+c][n] via a 32(n) x 64(c) LDS tile. Per-block double partials.
__global__ __launch_bounds__(256) void k_interp2(const float* __restrict__ pts,
                                                 const int* __restrict__ idx,
                                                 const float* __restrict__ w,
                                                 float* __restrict__ out,
                                                 double* __restrict__ partials) {
    __shared__ float tile[32][65];
    __shared__ int   si[32][3];
    __shared__ float sw[32][3];
    const int b = blockIdx.z, nt = blockIdx.y, cc = blockIdx.x;
    const int n0 = nt * 32, c0 = cc * 64;
    const int tid = threadIdx.x;
    if (tid < 32) {
        size_t p = ((size_t)b * 8192 + n0 + tid) * 3;
        si[tid][0] = idx[p]; si[tid][1] = idx[p + 1]; si[tid][2] = idx[p + 2];
        sw[tid][0] = w[p];   sw[tid][1] = w[p + 1];   sw[tid][2] = w[p + 2];
    }
    __syncthreads();
    const float* pb = pts + (size_t)b * 2048 * 768 + c0;
    const int cl = tid & 63;
    const int nl0 = tid >> 6;   // 0..3
    double ls = 0.0, lq = 0.0;
#pragma unroll
    for (int pass = 0; pass < 8; ++pass) {
        int nl = pass * 4 + nl0;
        float v = (sw[nl][0] * pb[(size_t)si[nl][0] * 768 + cl]
                 + sw[nl][1] * pb[(size_t)si[nl][1] * 768 + cl])
                 + sw[nl][2] * pb[(size_t)si[nl][2] * 768 + cl];
        tile[nl][cl] = v;
        ls += v; lq += (double)v * v;
    }
    __syncthreads();
    float* ob = out + (size_t)b * 896 * 8192 + (size_t)(128 + c0) * 8192 + n0;
    const int tn = tid & 31, tc0 = tid >> 5;  // 0..7
#pragma unroll
    for (int pass = 0; pass < 8; ++pass) {
        int tc = pass * 8 + tc0;
        ob[(size_t)tc * 8192 + tn] = tile[tn][tc];
    }
    __shared__ double sa[256], sb[256];
    sa[tid] = ls; sb[tid] = lq; __syncthreads();
    for (int s = 128; s > 0; s >>= 1) {
        if (tid < s) { sa[tid] += sa[tid + s]; sb[tid] += sb[tid + s]; }
        __syncthreads();
    }
    if (tid == 0) {
        size_t pl = ((size_t)b * gridDim.y + nt) * gridDim.x + cc;
        partials[2 * pl] = sa[0]; partials[2 * pl + 1] = sb[0];
    }
}

// Deterministic single-block reduction of partials -> stats {mean, 1/(std+1e-5)}.
__global__ __launch_bounds__(256) void k_finalize(const double* __restrict__ partials,
                                                  int P, double nelem,
                                                  float* __restrict__ stats) {
    __shared__ double sa[256], sb[256];
    double ls = 0.0, lq = 0.0;
    for (int i = threadIdx.x; i < P; i += 256) { ls += partials[2 * i]; lq += partials[2 * i + 1]; }
    const int t = threadIdx.x;
    sa[t] = ls; sb[t] = lq; __syncthreads();
    for (int s = 128; s > 0; s >>= 1) {
        if (t < s) { sa[t] += sa[t + s]; sb[t] += sb[t + s]; }
        __syncthreads();
    }
    if (t == 0) {
        double sum = sa[0], sq = sb[0];
        double m = sum / nelem;
        double var = (sq - sum * sum / nelem) / (nelem - 1.0);
        double sd = sqrt(var > 0.0 ? var : 0.0);
        stats[0] = (float)m;
        stats[1] = (float)(1.0 / (sd + 1e-5));
    }
}

// Normalize level-1 interp region in place: inter[:, :, 256:768].
__global__ __launch_bounds__(256) void k_norm1(float* __restrict__ inter,
                                               const float* __restrict__ stats) {
    const float m = stats[0], rs = stats[1];
    const size_t i = (size_t)blockIdx.x * 256 + threadIdx.x;   // < 8*2048*512 = 2^23
    const int c = (int)(i & 511);
    const size_t t = i >> 9;
    const int n = (int)(t & 2047);
    const int b = (int)(t >> 11);
    float* p = inter + ((size_t)b * 2048 + n) * 768 + 256 + c;
    *p = (*p - m) * rs;
}

// Normalize level-2 interp region of the output in place (float4).
__global__ __launch_bounds__(256) void k_norm2(float* __restrict__ out,
                                               const float* __restrict__ stats) {
    const float m = stats[0], rs = stats[1];
    const size_t i = (size_t)blockIdx.x * 256 + threadIdx.x;   // < 8 * 1572864
    const size_t per = (size_t)768 * 8192 / 4;                 // 1572864
    const size_t b = i / per;
    const size_t off = i - b * per;
    float4* p = (float4*)(out + b * (size_t)896 * 8192 + (size_t)128 * 8192) + off;
    float4 v = *p;
    v.x = (v.x - m) * rs; v.y = (v.y - m) * rs;
    v.z = (v.z - m) * rs; v.w = (v.w - m) * rs;
    *p = v;
}

// Copy x0 [8,128,8192] into out[:, 0:128, :] (float4).
__global__ __launch_bounds__(256) void k_copy0(const float* __restrict__ x0,
                                               float* __restrict__ out) {
    const size_t i = (size_t)blockIdx.x * 256 + threadIdx.x;   // < 8*262144
    const size_t b = i >> 18;                                  // 262144 = 2^18
    const size_t off = i & (((size_t)1 << 18) - 1);
    const float4* src = (const float4*)(x0 + b * (size_t)128 * 8192);
    float4* dst = (float4*)(out + b * (size_t)896 * 8192);
    dst[off] = src[off];
}

extern "C" void kernel_launch(void* const* d_in, const int* in_sizes, int n_in,
                              void* d_out, int out_size, void* d_ws, size_t ws_size,
                              hipStream_t stream) {
    const float* xyz0 = (const float*)d_in[0];
    const float* xyz1 = (const float*)d_in[1];
    const float* xyz2 = (const float*)d_in[2];
    const float* x0   = (const float*)d_in[3];
    const float* x1   = (const float*)d_in[4];
    const float* x2   = (const float*)d_in[5];
    float* out = (float*)d_out;
    char* ws = (char*)d_ws;

    size_t off = 0;
    auto alloc = [&](size_t bytes) {
        size_t o = off;
        off = (off + bytes + 255) & ~(size_t)255;
        return o;
    };
    float*  stats    = (float*)(ws + alloc(4 * sizeof(float)));
    double* partials = (double*)(ws + alloc((size_t)24576 * 2 * sizeof(double)));
    int*    idx1     = (int*)(ws + alloc((size_t)8 * 2048 * 3 * 4));
    float*  w1       = (float*)(ws + alloc((size_t)8 * 2048 * 3 * 4));
    int*    idx2     = (int*)(ws + alloc((size_t)8 * 8192 * 3 * 4));
    float*  w2       = (float*)(ws + alloc((size_t)8 * 8192 * 3 * 4));
    float*  pts1     = (float*)(ws + alloc((size_t)8 * 512 * 512 * 4));   // x2^T  [8,512,512]
    float*  inter    = (float*)(ws + alloc((size_t)8 * 2048 * 768 * 4));  // level-1 out, [8,2048,768]

    // knn candidate scratch overlaps pts1/inter (knn runs before the transposes).
    float* cand_d2 = inter;                                   // 65536*24 f32 = 6.3 MB
    int*   cand_i2 = (int*)(inter + (size_t)65536 * 24);      // 6.3 MB (inter is 50 MB)
    float* cand_d1 = pts1;                                    // 16384*12 f32 = 0.8 MB
    int*   cand_i1 = (int*)(pts1 + (size_t)16384 * 12);       // 0.8 MB (pts1 is 8.4 MB)

    // ---- kNN for both levels first (scratch still free) ----
    k_knn_chunk<256><<<dim3(8192 / 256, 8, 8), 256, 0, stream>>>(
        xyz0, xyz1, 8192, 2048, cand_d2, cand_i2);
    k_knn_merge<<<(8 * 8192) / 256, 256, 0, stream>>>(cand_d2, cand_i2, 8 * 8192, 24, idx2, w2);
    k_knn_chunk<128><<<dim3(2048 / 256, 4, 8), 256, 0, stream>>>(
        xyz1, xyz2, 2048, 512, cand_d1, cand_i1);
    k_knn_merge<<<(8 * 2048) / 256, 256, 0, stream>>>(cand_d1, cand_i1, 8 * 2048, 12, idx1, w1);

    // ---- level 1: propagate(xyz1, xyz2, x1, x2) -> inter [8,2048,768] ----
    k_transpose<<<dim3(512 / 32, 512 / 32, 8), dim3(32, 8), 0, stream>>>(
        x2, pts1, 512, 512, 512 * 512, 512 * 512, 512);
    k_transpose<<<dim3(2048 / 32, 256 / 32, 8), dim3(32, 8), 0, stream>>>(
        x1, inter, 256, 2048, 256 * 2048, 2048 * 768, 768);
    k_interp1<<<dim3(2048, 8), 256, 0, stream>>>(pts1, idx1, w1, inter, partials);
    k_finalize<<<1, 256, 0, stream>>>(partials, 16384, (double)8 * 2048 * 512, stats);
    k_norm1<<<(8 * 2048 * 512) / 256, 256, 0, stream>>>(inter, stats);

    // ---- level 2: propagate(xyz0, xyz1, x0, inter^T) -> out [8,896,8192] ----
    k_interp2<<<dim3(12, 256, 8), 256, 0, stream>>>(inter, idx2, w2, out, partials);
    k_finalize<<<1, 256, 0, stream>>>(partials, 24576, (double)8 * 8192 * 768, stats + 2);
    k_norm2<<<(8 * 1572864) / 256, 256, 0, stream>>>(out, stats + 2);
    k_copy0<<<(8 * 262144) / 256, 256, 0, stream>>>(x0, out);
}

// Round 3
// 289.611 us; speedup vs baseline: 2.2466x; 1.1000x over previous
//
#include <hip/hip_runtime.h>
#include <cstdint>
#include <math.h>

// ---------------------------------------------------------------------------
// Problem constants (from setup_inputs)
//   B=8
//   level 1: fine xyz1 [8,2048,3], coarse xyz2 [8,512,3], x1 [8,256,2048], x2 [8,512,512]
//   level 2: fine xyz0 [8,8192,3], coarse xyz1 [8,2048,3], x0 [8,128,8192]
//   out [8, 896, 8192] f32
// Structure: stats are computed by a read-only gather pass (sources are
// L2/LLC-resident), then the write pass emits normalized values once.
// ---------------------------------------------------------------------------

// Tiled transpose: in [B, R, C] row-major -> out[b][c][r] with out row stride out_rs.
__global__ __launch_bounds__(256) void k_transpose(const float* __restrict__ in,
                                                   float* __restrict__ out,
                                                   int R, int C,
                                                   long in_bs, long out_bs, int out_rs) {
    __shared__ float tile[32][33];
    const int b = blockIdx.z;
    const int r0 = blockIdx.y * 32;
    const int c0 = blockIdx.x * 32;
    const float* inb = in + (size_t)b * in_bs;
    float* outb = out + (size_t)b * out_bs;
    const int tx = threadIdx.x;   // 0..31
    const int ty = threadIdx.y;   // 0..7
#pragma unroll
    for (int i = 0; i < 32; i += 8) {
        tile[ty + i][tx] = inb[(size_t)(r0 + ty + i) * C + (c0 + tx)];
    }
    __syncthreads();
#pragma unroll
    for (int i = 0; i < 32; i += 8) {
        outb[(size_t)(c0 + ty + i) * out_rs + (r0 + tx)] = tile[tx][ty + i];
    }
}

// Chunked brute-force 3-NN: each block scans CHUNK coarse points for 256 fine
// points, writes a sorted local top-3 (d, global_s) per point per chunk.
template <int CHUNK>
__global__ __launch_bounds__(256) void k_knn_chunk(const float* __restrict__ fine,
                                                   const float* __restrict__ coarse,
                                                   int N, int S,
                                                   float* __restrict__ cand_d,
                                                   int* __restrict__ cand_i) {
#pragma clang fp contract(off)
    __shared__ float4 lc[CHUNK];
    const int b = blockIdx.z;
    const int chunk = blockIdx.y;
    const int nch = gridDim.y;
    const int n = blockIdx.x * 256 + threadIdx.x;
    const int s0 = chunk * CHUNK;
    const float* cb = coarse + ((size_t)b * S + s0) * 3;
    for (int s = threadIdx.x; s < CHUNK; s += 256) {
        float x = cb[3 * s], y = cb[3 * s + 1], z = cb[3 * s + 2];
        lc[s] = make_float4(x, y, z, (x * x + y * y) + z * z);
    }
    __syncthreads();
    const float* fp = fine + ((size_t)b * N + n) * 3;
    const float px = fp[0], py = fp[1], pz = fp[2];
    const float psq = (px * px + py * py) + pz * pz;
    float d0 = 1e30f, d1 = 1e30f, d2 = 1e30f;
    int i0 = 0, i1 = 0, i2 = 0;
#pragma unroll 4
    for (int s = 0; s < CHUNK; ++s) {
        float4 c = lc[s];
        float dot = (px * c.x + py * c.y) + pz * c.z;
        float d = fmaf(-2.0f, dot, psq + c.w);
        const bool lt0 = d < d0, lt1 = d < d1, lt2 = d < d2;
        d2 = lt1 ? d1 : (lt2 ? d : d2);
        i2 = lt1 ? i1 : (lt2 ? s : i2);
        d1 = lt0 ? d0 : (lt1 ? d : d1);
        i1 = lt0 ? i0 : (lt1 ? s : i1);
        d0 = lt0 ? d : d0;
        i0 = lt0 ? s : i0;
    }
    const size_t p = (((size_t)b * N + n) * nch + chunk) * 3;
    cand_d[p] = d0; cand_d[p + 1] = d1; cand_d[p + 2] = d2;
    cand_i[p] = s0 + i0; cand_i[p + 1] = s0 + i1; cand_i[p + 2] = s0 + i2;
}

// Merge per-chunk candidates (chunk-major, each chunk sorted ascending) into
// the final top-3 + normalized inverse-distance weights. Strict < keeps the
// earlier (lower-index) candidate on ties, matching top_k tie-breaking.
__global__ __launch_bounds__(256) void k_knn_merge(const float* __restrict__ cand_d,
                                                   const int* __restrict__ cand_i,
                                                   int npts, int ncand,
                                                   int* __restrict__ idx,
                                                   float* __restrict__ wout) {
    const int p = blockIdx.x * 256 + threadIdx.x;
    if (p >= npts) return;
    const float* cd = cand_d + (size_t)p * ncand;
    const int*   ci = cand_i + (size_t)p * ncand;
    float d0 = 1e30f, d1 = 1e30f, d2 = 1e30f;
    int i0 = 0, i1 = 0, i2 = 0;
    for (int k = 0; k < ncand; ++k) {
        const float d = cd[k];
        const int s = ci[k];
        const bool lt0 = d < d0, lt1 = d < d1, lt2 = d < d2;
        d2 = lt1 ? d1 : (lt2 ? d : d2);
        i2 = lt1 ? i1 : (lt2 ? s : i2);
        d1 = lt0 ? d0 : (lt1 ? d : d1);
        i1 = lt0 ? i0 : (lt1 ? s : i1);
        d0 = lt0 ? d : d0;
        i0 = lt0 ? s : i0;
    }
    const float w0 = 1.0f / (d0 + 1e-8f);
    const float w1 = 1.0f / (d1 + 1e-8f);
    const float w2 = 1.0f / (d2 + 1e-8f);
    const float wsum = (w0 + w1) + w2;
    const size_t q = (size_t)p * 3;
    idx[q] = i0; idx[q + 1] = i1; idx[q + 2] = i2;
    wout[q] = w0 / wsum; wout[q + 1] = w1 / wsum; wout[q + 2] = w2 / wsum;
}

// Generic stats-only gather pass: block handles 32 fine points x C cols of
// pts [B,S,C]; accumulates double sum/sumsq of interp values, no writes.
// C = CITER*256.
template <int CITER>
__global__ __launch_bounds__(256) void k_interp_stats(const float* __restrict__ pts,
                                                      const int* __restrict__ idx,
                                                      const float* __restrict__ w,
                                                      int N, int C,
                                                      double* __restrict__ partials) {
    __shared__ int   si[32][3];
    __shared__ float sw[32][3];
    const int b = blockIdx.y, nb = blockIdx.x;
    const int n0 = nb * 32;
    const int tid = threadIdx.x;
    if (tid < 32) {
        size_t p = ((size_t)b * N + n0 + tid) * 3;
        si[tid][0] = idx[p]; si[tid][1] = idx[p + 1]; si[tid][2] = idx[p + 2];
        sw[tid][0] = w[p];   sw[tid][1] = w[p + 1];   sw[tid][2] = w[p + 2];
    }
    __syncthreads();
    const float* pb = pts + (size_t)b * ((size_t)C == 768 ? 2048 : 512) * C;
    double ls = 0.0, lq = 0.0;
    for (int nl = 0; nl < 32; ++nl) {
        const float* r0 = pb + (size_t)si[nl][0] * C;
        const float* r1 = pb + (size_t)si[nl][1] * C;
        const float* r2 = pb + (size_t)si[nl][2] * C;
        const float w0 = sw[nl][0], w1 = sw[nl][1], w2 = sw[nl][2];
#pragma unroll
        for (int cc = 0; cc < CITER; ++cc) {
            int c = cc * 256 + tid;
            float v = (w0 * r0[c] + w1 * r1[c]) + w2 * r2[c];
            ls += v; lq += (double)v * v;
        }
    }
    __shared__ double sa[256], sb[256];
    sa[tid] = ls; sb[tid] = lq; __syncthreads();
    for (int s = 128; s > 0; s >>= 1) {
        if (tid < s) { sa[tid] += sa[tid + s]; sb[tid] += sb[tid + s]; }
        __syncthreads();
    }
    if (tid == 0) {
        size_t pl = (size_t)b * gridDim.x + nb;
        partials[2 * pl] = sa[0]; partials[2 * pl + 1] = sb[0];
    }
}

// Deterministic single-block reduction of partials -> stats {mean, 1/(std+1e-5)}.
__global__ __launch_bounds__(256) void k_finalize(const double* __restrict__ partials,
                                                  int P, double nelem,
                                                  float* __restrict__ stats) {
    __shared__ double sa[256], sb[256];
    double ls = 0.0, lq = 0.0;
    for (int i = threadIdx.x; i < P; i += 256) { ls += partials[2 * i]; lq += partials[2 * i + 1]; }
    const int t = threadIdx.x;
    sa[t] = ls; sb[t] = lq; __syncthreads();
    for (int s = 128; s > 0; s >>= 1) {
        if (t < s) { sa[t] += sa[t + s]; sb[t] += sb[t + s]; }
        __syncthreads();
    }
    if (t == 0) {
        double sum = sa[0], sq = sb[0];
        double m = sum / nelem;
        double var = (sq - sum * sum / nelem) / (nelem - 1.0);
        double sd = sqrt(var > 0.0 ? var : 0.0);
        stats[0] = (float)m;
        stats[1] = (float)(1.0 / (sd + 1e-5));
    }
}

// Level-1 write pass: gather rows of pts1 [8,512,512], normalize, write
// inter[b][n][256+c] (coalesced). Values recomputed identically to stats pass.
__global__ __launch_bounds__(256) void k_interp1_write(const float* __restrict__ pts,
                                                       const int* __restrict__ idx,
                                                       const float* __restrict__ w,
                                                       const float* __restrict__ stats,
                                                       float* __restrict__ inter) {
    const float m = stats[0], rs = stats[1];
    const int b = blockIdx.y, n = blockIdx.x;
    const size_t p = (size_t)b * 2048 + n;
    const int i0 = idx[p * 3], i1 = idx[p * 3 + 1], i2 = idx[p * 3 + 2];
    const float w0 = w[p * 3], w1 = w[p * 3 + 1], w2 = w[p * 3 + 2];
    const float* pb = pts + (size_t)b * 512 * 512;
    const float* r0 = pb + (size_t)i0 * 512;
    const float* r1 = pb + (size_t)i1 * 512;
    const float* r2 = pb + (size_t)i2 * 512;
    float* outp = inter + p * 768 + 256;
#pragma unroll
    for (int cc = 0; cc < 2; ++cc) {
        int c = threadIdx.x + cc * 256;
        float v = (w0 * r0[c] + w1 * r1[c]) + w2 * r2[c];
        outp[c] = (v - m) * rs;
    }
}

// Level-2 write pass: gather rows of inter [8,2048,768], normalize, write
// TRANSPOSED into out[b][128+c][n] via a 32(n) x 64(c) LDS tile.
__global__ __launch_bounds__(256) void k_interp2_write(const float* __restrict__ pts,
                                                       const int* __restrict__ idx,
                                                       const float* __restrict__ w,
                                                       const float* __restrict__ stats,
                                                       float* __restrict__ out) {
    __shared__ float tile[32][65];
    __shared__ int   si[32][3];
    __shared__ float sw[32][3];
    const float m = stats[0], rs = stats[1];
    const int b = blockIdx.z, nt = blockIdx.y, cc = blockIdx.x;
    const int n0 = nt * 32, c0 = cc * 64;
    const int tid = threadIdx.x;
    if (tid < 32) {
        size_t p = ((size_t)b * 8192 + n0 + tid) * 3;
        si[tid][0] = idx[p]; si[tid][1] = idx[p + 1]; si[tid][2] = idx[p + 2];
        sw[tid][0] = w[p];   sw[tid][1] = w[p + 1];   sw[tid][2] = w[p + 2];
    }
    __syncthreads();
    const float* pb = pts + (size_t)b * 2048 * 768 + c0;
    const int cl = tid & 63;
    const int nl0 = tid >> 6;   // 0..3
#pragma unroll
    for (int pass = 0; pass < 8; ++pass) {
        int nl = pass * 4 + nl0;
        float v = (sw[nl][0] * pb[(size_t)si[nl][0] * 768 + cl]
                 + sw[nl][1] * pb[(size_t)si[nl][1] * 768 + cl])
                 + sw[nl][2] * pb[(size_t)si[nl][2] * 768 + cl];
        tile[nl][cl] = (v - m) * rs;
    }
    __syncthreads();
    float* ob = out + (size_t)b * 896 * 8192 + (size_t)(128 + c0) * 8192 + n0;
    const int tn = tid & 31, tc0 = tid >> 5;  // 0..7
#pragma unroll
    for (int pass = 0; pass < 8; ++pass) {
        int tc = pass * 8 + tc0;
        ob[(size_t)tc * 8192 + tn] = tile[tn][tc];
    }
}

// Copy x0 [8,128,8192] into out[:, 0:128, :] (float4).
__global__ __launch_bounds__(256) void k_copy0(const float* __restrict__ x0,
                                               float* __restrict__ out) {
    const size_t i = (size_t)blockIdx.x * 256 + threadIdx.x;   // < 8*262144
    const size_t b = i >> 18;                                  // 262144 = 2^18
    const size_t off = i & (((size_t)1 << 18) - 1);
    const float4* src = (const float4*)(x0 + b * (size_t)128 * 8192);
    float4* dst = (float4*)(out + b * (size_t)896 * 8192);
    dst[off] = src[off];
}

extern "C" void kernel_launch(void* const* d_in, const int* in_sizes, int n_in,
                              void* d_out, int out_size, void* d_ws, size_t ws_size,
                              hipStream_t stream) {
    const float* xyz0 = (const float*)d_in[0];
    const float* xyz1 = (const float*)d_in[1];
    const float* xyz2 = (const float*)d_in[2];
    const float* x0   = (const float*)d_in[3];
    const float* x1   = (const float*)d_in[4];
    const float* x2   = (const float*)d_in[5];
    float* out = (float*)d_out;
    char* ws = (char*)d_ws;

    size_t off = 0;
    auto alloc = [&](size_t bytes) {
        size_t o = off;
        off = (off + bytes + 255) & ~(size_t)255;
        return o;
    };
    float*  stats    = (float*)(ws + alloc(4 * sizeof(float)));
    double* partials = (double*)(ws + alloc((size_t)4096 * 2 * sizeof(double)));
    int*    idx1     = (int*)(ws + alloc((size_t)8 * 2048 * 3 * 4));
    float*  w1       = (float*)(ws + alloc((size_t)8 * 2048 * 3 * 4));
    int*    idx2     = (int*)(ws + alloc((size_t)8 * 8192 * 3 * 4));
    float*  w2       = (float*)(ws + alloc((size_t)8 * 8192 * 3 * 4));
    float*  pts1     = (float*)(ws + alloc((size_t)8 * 512 * 512 * 4));   // x2^T  [8,512,512]
    float*  inter    = (float*)(ws + alloc((size_t)8 * 2048 * 768 * 4));  // level-1 out, [8,2048,768]

    // knn candidate scratch overlaps pts1/inter (knn runs before the transposes).
    float* cand_d2 = inter;                                   // 65536*24 f32 = 6.3 MB
    int*   cand_i2 = (int*)(inter + (size_t)65536 * 24);      // 6.3 MB (inter is 50 MB)
    float* cand_d1 = pts1;                                    // 16384*12 f32 = 0.8 MB
    int*   cand_i1 = (int*)(pts1 + (size_t)16384 * 12);       // 0.8 MB (pts1 is 8.4 MB)

    // ---- kNN for both levels first (scratch still free) ----
    k_knn_chunk<256><<<dim3(8192 / 256, 8, 8), 256, 0, stream>>>(
        xyz0, xyz1, 8192, 2048, cand_d2, cand_i2);
    k_knn_merge<<<(8 * 8192) / 256, 256, 0, stream>>>(cand_d2, cand_i2, 8 * 8192, 24, idx2, w2);
    k_knn_chunk<128><<<dim3(2048 / 256, 4, 8), 256, 0, stream>>>(
        xyz1, xyz2, 2048, 512, cand_d1, cand_i1);
    k_knn_merge<<<(8 * 2048) / 256, 256, 0, stream>>>(cand_d1, cand_i1, 8 * 2048, 12, idx1, w1);

    // ---- level 1: propagate(xyz1, xyz2, x1, x2) -> inter [8,2048,768] ----
    k_transpose<<<dim3(512 / 32, 512 / 32, 8), dim3(32, 8), 0, stream>>>(
        x2, pts1, 512, 512, 512 * 512, 512 * 512, 512);
    k_transpose<<<dim3(2048 / 32, 256 / 32, 8), dim3(32, 8), 0, stream>>>(
        x1, inter, 256, 2048, 256 * 2048, 2048 * 768, 768);
    k_interp_stats<2><<<dim3(2048 / 32, 8), 256, 0, stream>>>(
        pts1, idx1, w1, 2048, 512, partials);
    k_finalize<<<1, 256, 0, stream>>>(partials, 512, (double)8 * 2048 * 512, stats);
    k_interp1_write<<<dim3(2048, 8), 256, 0, stream>>>(pts1, idx1, w1, stats, inter);

    // ---- level 2: propagate(xyz0, xyz1, x0, inter^T) -> out [8,896,8192] ----
    k_interp_stats<3><<<dim3(8192 / 32, 8), 256, 0, stream>>>(
        inter, idx2, w2, 8192, 768, partials);
    k_finalize<<<1, 256, 0, stream>>>(partials, 2048, (double)8 * 8192 * 768, stats + 2);
    k_interp2_write<<<dim3(12, 256, 8), 256, 0, stream>>>(inter, idx2, w2, stats + 2, out);
    k_copy0<<<(8 * 262144) / 256, 256, 0, stream>>>(x0, out);
}

// Round 4
// 242.208 us; speedup vs baseline: 2.6862x; 1.1957x over previous
//
#include <hip/hip_runtime.h>
#include <cstdint>
#include <math.h>

// ---------------------------------------------------------------------------
// Problem constants (from setup_inputs)
//   B=8
//   level 1: fine xyz1 [8,2048,3], coarse xyz2 [8,512,3], x1 [8,256,2048], x2 [8,512,512]
//   level 2: fine xyz0 [8,8192,3], coarse xyz1 [8,2048,3], x0 [8,128,8192]
//   out [8, 896, 8192] f32
// Structure: read-only stats gather pass (sources L2-resident, XCD-pinned per
// batch), then a write pass emits normalized values once.
// Grids for gather passes use blockIdx.x = batch so linear block id % 8 == b
// -> round-robin dispatch pins each batch's blocks to one XCD's L2.
// ---------------------------------------------------------------------------

// Tiled transpose: in [B, R, C] row-major -> out[b][c][r] with out row stride out_rs.
__global__ __launch_bounds__(256) void k_transpose(const float* __restrict__ in,
                                                   float* __restrict__ out,
                                                   int R, int C,
                                                   long in_bs, long out_bs, int out_rs) {
    __shared__ float tile[32][33];
    const int b = blockIdx.z;
    const int r0 = blockIdx.y * 32;
    const int c0 = blockIdx.x * 32;
    const float* inb = in + (size_t)b * in_bs;
    float* outb = out + (size_t)b * out_bs;
    const int tx = threadIdx.x;   // 0..31
    const int ty = threadIdx.y;   // 0..7
#pragma unroll
    for (int i = 0; i < 32; i += 8) {
        tile[ty + i][tx] = inb[(size_t)(r0 + ty + i) * C + (c0 + tx)];
    }
    __syncthreads();
#pragma unroll
    for (int i = 0; i < 32; i += 8) {
        outb[(size_t)(c0 + ty + i) * out_rs + (r0 + tx)] = tile[tx][ty + i];
    }
}

// Chunked brute-force 3-NN: each block scans CHUNK coarse points for 256 fine
// points, writes a sorted local top-3 (d, global_s) per point per chunk.
// The top-3 update is guarded by a uniform __any branch: most iterations no
// lane improves its top-3, so the 9-op cndmask chain is skipped wave-wide.
template <int CHUNK>
__global__ __launch_bounds__(256) void k_knn_chunk(const float* __restrict__ fine,
                                                   const float* __restrict__ coarse,
                                                   int N, int S,
                                                   float* __restrict__ cand_d,
                                                   int* __restrict__ cand_i) {
#pragma clang fp contract(off)
    __shared__ float4 lc[CHUNK];
    const int b = blockIdx.z;
    const int chunk = blockIdx.y;
    const int nch = gridDim.y;
    const int n = blockIdx.x * 256 + threadIdx.x;
    const int s0 = chunk * CHUNK;
    const float* cb = coarse + ((size_t)b * S + s0) * 3;
    for (int s = threadIdx.x; s < CHUNK; s += 256) {
        float x = cb[3 * s], y = cb[3 * s + 1], z = cb[3 * s + 2];
        lc[s] = make_float4(x, y, z, (x * x + y * y) + z * z);
    }
    __syncthreads();
    const float* fp = fine + ((size_t)b * N + n) * 3;
    const float px = fp[0], py = fp[1], pz = fp[2];
    const float psq = (px * px + py * py) + pz * pz;
    float d0 = 1e30f, d1 = 1e30f, d2 = 1e30f;
    int i0 = 0, i1 = 0, i2 = 0;
#pragma unroll 2
    for (int s = 0; s < CHUNK; ++s) {
        float4 c = lc[s];
        float dot = (px * c.x + py * c.y) + pz * c.z;
        float d = fmaf(-2.0f, dot, psq + c.w);
        if (__any(d < d2)) {
            const bool lt0 = d < d0, lt1 = d < d1, lt2 = d < d2;
            d2 = lt1 ? d1 : (lt2 ? d : d2);
            i2 = lt1 ? i1 : (lt2 ? s : i2);
            d1 = lt0 ? d0 : (lt1 ? d : d1);
            i1 = lt0 ? i0 : (lt1 ? s : i1);
            d0 = lt0 ? d : d0;
            i0 = lt0 ? s : i0;
        }
    }
    const size_t p = (((size_t)b * N + n) * nch + chunk) * 3;
    cand_d[p] = d0; cand_d[p + 1] = d1; cand_d[p + 2] = d2;
    cand_i[p] = s0 + i0; cand_i[p + 1] = s0 + i1; cand_i[p + 2] = s0 + i2;
}

// Merge per-chunk candidates (chunk-major, each chunk sorted ascending) into
// the final top-3 + normalized inverse-distance weights. Strict < keeps the
// earlier (lower-index) candidate on ties, matching top_k tie-breaking.
__global__ __launch_bounds__(256) void k_knn_merge(const float* __restrict__ cand_d,
                                                   const int* __restrict__ cand_i,
                                                   int npts, int ncand,
                                                   int* __restrict__ idx,
                                                   float* __restrict__ wout) {
    const int p = blockIdx.x * 256 + threadIdx.x;
    if (p >= npts) return;
    const float* cd = cand_d + (size_t)p * ncand;
    const int*   ci = cand_i + (size_t)p * ncand;
    float d0 = 1e30f, d1 = 1e30f, d2 = 1e30f;
    int i0 = 0, i1 = 0, i2 = 0;
    for (int k = 0; k < ncand; ++k) {
        const float d = cd[k];
        const int s = ci[k];
        const bool lt0 = d < d0, lt1 = d < d1, lt2 = d < d2;
        d2 = lt1 ? d1 : (lt2 ? d : d2);
        i2 = lt1 ? i1 : (lt2 ? s : i2);
        d1 = lt0 ? d0 : (lt1 ? d : d1);
        i1 = lt0 ? i0 : (lt1 ? s : i1);
        d0 = lt0 ? d : d0;
        i0 = lt0 ? s : i0;
    }
    const float w0 = 1.0f / (d0 + 1e-8f);
    const float w1 = 1.0f / (d1 + 1e-8f);
    const float w2 = 1.0f / (d2 + 1e-8f);
    const float wsum = (w0 + w1) + w2;
    const size_t q = (size_t)p * 3;
    idx[q] = i0; idx[q + 1] = i1; idx[q + 2] = i2;
    wout[q] = w0 / wsum; wout[q + 1] = w1 / wsum; wout[q + 2] = w2 / wsum;
}

// Stats-only gather pass: grid (x=B, y=N/32, z=C/256).
// Block handles 32 fine points x 256 cols at col base blockIdx.z*256 of
// pts [B,S,C]; accumulates double sum/sumsq, no writes. Per-(b,z) working set
// = S*256*4 B (<= 2 MB) -> L2-resident on the batch's XCD.
__global__ __launch_bounds__(256) void k_interp_stats(const float* __restrict__ pts,
                                                      const int* __restrict__ idx,
                                                      const float* __restrict__ w,
                                                      int N, int S, int C,
                                                      double* __restrict__ partials) {
    __shared__ int   si[32][3];
    __shared__ float sw[32][3];
    const int b = blockIdx.x, nb = blockIdx.y, cb = blockIdx.z;
    const int n0 = nb * 32;
    const int tid = threadIdx.x;
    if (tid < 32) {
        size_t p = ((size_t)b * N + n0 + tid) * 3;
        si[tid][0] = idx[p]; si[tid][1] = idx[p + 1]; si[tid][2] = idx[p + 2];
        sw[tid][0] = w[p];   sw[tid][1] = w[p + 1];   sw[tid][2] = w[p + 2];
    }
    __syncthreads();
    const float* pb = pts + (size_t)b * S * C + cb * 256 + tid;
    double ls = 0.0, lq = 0.0;
    for (int nl = 0; nl < 32; ++nl) {
        float v = (sw[nl][0] * pb[(size_t)si[nl][0] * C]
                 + sw[nl][1] * pb[(size_t)si[nl][1] * C])
                 + sw[nl][2] * pb[(size_t)si[nl][2] * C];
        ls += v; lq += (double)v * v;
    }
    __shared__ double sa[256], sb[256];
    sa[tid] = ls; sb[tid] = lq; __syncthreads();
    for (int s = 128; s > 0; s >>= 1) {
        if (tid < s) { sa[tid] += sa[tid + s]; sb[tid] += sb[tid + s]; }
        __syncthreads();
    }
    if (tid == 0) {
        size_t pl = ((size_t)cb * gridDim.x + b) * gridDim.y + nb;
        partials[2 * pl] = sa[0]; partials[2 * pl + 1] = sb[0];
    }
}

// Deterministic single-block reduction of partials -> stats {mean, 1/(std+1e-5)}.
__global__ __launch_bounds__(256) void k_finalize(const double* __restrict__ partials,
                                                  int P, double nelem,
                                                  float* __restrict__ stats) {
    __shared__ double sa[256], sb[256];
    double ls = 0.0, lq = 0.0;
    for (int i = threadIdx.x; i < P; i += 256) { ls += partials[2 * i]; lq += partials[2 * i + 1]; }
    const int t = threadIdx.x;
    sa[t] = ls; sb[t] = lq; __syncthreads();
    for (int s = 128; s > 0; s >>= 1) {
        if (t < s) { sa[t] += sa[t + s]; sb[t] += sb[t + s]; }
        __syncthreads();
    }
    if (t == 0) {
        double sum = sa[0], sq = sb[0];
        double m = sum / nelem;
        double var = (sq - sum * sum / nelem) / (nelem - 1.0);
        double sd = sqrt(var > 0.0 ? var : 0.0);
        stats[0] = (float)m;
        stats[1] = (float)(1.0 / (sd + 1e-5));
    }
}

// Level-1 write pass: grid (x=B, y=N). Gather rows of pts1 [8,512,512],
// normalize, write inter[b][n][256+c] (coalesced).
__global__ __launch_bounds__(256) void k_interp1_write(const float* __restrict__ pts,
                                                       const int* __restrict__ idx,
                                                       const float* __restrict__ w,
                                                       const float* __restrict__ stats,
                                                       float* __restrict__ inter) {
    const float m = stats[0], rs = stats[1];
    const int b = blockIdx.x, n = blockIdx.y;
    const size_t p = (size_t)b * 2048 + n;
    const int i0 = idx[p * 3], i1 = idx[p * 3 + 1], i2 = idx[p * 3 + 2];
    const float w0 = w[p * 3], w1 = w[p * 3 + 1], w2 = w[p * 3 + 2];
    const float* pb = pts + (size_t)b * 512 * 512;
    const float* r0 = pb + (size_t)i0 * 512;
    const float* r1 = pb + (size_t)i1 * 512;
    const float* r2 = pb + (size_t)i2 * 512;
    float* outp = inter + p * 768 + 256;
#pragma unroll
    for (int cc = 0; cc < 2; ++cc) {
        int c = threadIdx.x + cc * 256;
        float v = (w0 * r0[c] + w1 * r1[c]) + w2 * r2[c];
        outp[c] = (v - m) * rs;
    }
}

// Level-2 write pass: grid (x=B, y=256 n-tiles, z=12 c-blocks). Gather rows of
// inter [8,2048,768], normalize, write TRANSPOSED into out[b][128+c][n] via a
// 32(n) x 64(c) LDS tile. Per-(b,z) working set = 2048*64*4 = 0.5 MB -> L2.
__global__ __launch_bounds__(256) void k_interp2_write(const float* __restrict__ pts,
                                                       const int* __restrict__ idx,
                                                       const float* __restrict__ w,
                                                       const float* __restrict__ stats,
                                                       float* __restrict__ out) {
    __shared__ float tile[32][65];
    __shared__ int   si[32][3];
    __shared__ float sw[32][3];
    const float m = stats[0], rs = stats[1];
    const int b = blockIdx.x, nt = blockIdx.y, cc = blockIdx.z;
    const int n0 = nt * 32, c0 = cc * 64;
    const int tid = threadIdx.x;
    if (tid < 32) {
        size_t p = ((size_t)b * 8192 + n0 + tid) * 3;
        si[tid][0] = idx[p]; si[tid][1] = idx[p + 1]; si[tid][2] = idx[p + 2];
        sw[tid][0] = w[p];   sw[tid][1] = w[p + 1];   sw[tid][2] = w[p + 2];
    }
    __syncthreads();
    const float* pb = pts + (size_t)b * 2048 * 768 + c0;
    const int cl = tid & 63;
    const int nl0 = tid >> 6;   // 0..3
#pragma unroll
    for (int pass = 0; pass < 8; ++pass) {
        int nl = pass * 4 + nl0;
        float v = (sw[nl][0] * pb[(size_t)si[nl][0] * 768 + cl]
                 + sw[nl][1] * pb[(size_t)si[nl][1] * 768 + cl])
                 + sw[nl][2] * pb[(size_t)si[nl][2] * 768 + cl];
        tile[nl][cl] = (v - m) * rs;
    }
    __syncthreads();
    float* ob = out + (size_t)b * 896 * 8192 + (size_t)(128 + c0) * 8192 + n0;
    const int tn = tid & 31, tc0 = tid >> 5;  // 0..7
#pragma unroll
    for (int pass = 0; pass < 8; ++pass) {
        int tc = pass * 8 + tc0;
        ob[(size_t)tc * 8192 + tn] = tile[tn][tc];
    }
}

// Copy x0 [8,128,8192] into out[:, 0:128, :] (float4).
__global__ __launch_bounds__(256) void k_copy0(const float* __restrict__ x0,
                                               float* __restrict__ out) {
    const size_t i = (size_t)blockIdx.x * 256 + threadIdx.x;   // < 8*262144
    const size_t b = i >> 18;                                  // 262144 = 2^18
    const size_t off = i & (((size_t)1 << 18) - 1);
    const float4* src = (const float4*)(x0 + b * (size_t)128 * 8192);
    float4* dst = (float4*)(out + b * (size_t)896 * 8192);
    dst[off] = src[off];
}

extern "C" void kernel_launch(void* const* d_in, const int* in_sizes, int n_in,
                              void* d_out, int out_size, void* d_ws, size_t ws_size,
                              hipStream_t stream) {
    const float* xyz0 = (const float*)d_in[0];
    const float* xyz1 = (const float*)d_in[1];
    const float* xyz2 = (const float*)d_in[2];
    const float* x0   = (const float*)d_in[3];
    const float* x1   = (const float*)d_in[4];
    const float* x2   = (const float*)d_in[5];
    float* out = (float*)d_out;
    char* ws = (char*)d_ws;

    size_t off = 0;
    auto alloc = [&](size_t bytes) {
        size_t o = off;
        off = (off + bytes + 255) & ~(size_t)255;
        return o;
    };
    float*  stats    = (float*)(ws + alloc(4 * sizeof(float)));
    double* partials = (double*)(ws + alloc((size_t)6144 * 2 * sizeof(double)));
    int*    idx1     = (int*)(ws + alloc((size_t)8 * 2048 * 3 * 4));
    float*  w1       = (float*)(ws + alloc((size_t)8 * 2048 * 3 * 4));
    int*    idx2     = (int*)(ws + alloc((size_t)8 * 8192 * 3 * 4));
    float*  w2       = (float*)(ws + alloc((size_t)8 * 8192 * 3 * 4));
    float*  pts1     = (float*)(ws + alloc((size_t)8 * 512 * 512 * 4));   // x2^T  [8,512,512]
    float*  inter    = (float*)(ws + alloc((size_t)8 * 2048 * 768 * 4));  // level-1 out, [8,2048,768]

    // knn candidate scratch overlaps pts1/inter (knn runs before the transposes).
    float* cand_d2 = inter;                                   // 65536*24 f32 = 6.3 MB
    int*   cand_i2 = (int*)(inter + (size_t)65536 * 24);      // 6.3 MB (inter is 50 MB)
    float* cand_d1 = pts1;                                    // 16384*12 f32 = 0.8 MB
    int*   cand_i1 = (int*)(pts1 + (size_t)16384 * 12);       // 0.8 MB (pts1 is 8.4 MB)

    // ---- kNN for both levels first (scratch still free) ----
    k_knn_chunk<256><<<dim3(8192 / 256, 8, 8), 256, 0, stream>>>(
        xyz0, xyz1, 8192, 2048, cand_d2, cand_i2);
    k_knn_merge<<<(8 * 8192) / 256, 256, 0, stream>>>(cand_d2, cand_i2, 8 * 8192, 24, idx2, w2);
    k_knn_chunk<128><<<dim3(2048 / 256, 4, 8), 256, 0, stream>>>(
        xyz1, xyz2, 2048, 512, cand_d1, cand_i1);
    k_knn_merge<<<(8 * 2048) / 256, 256, 0, stream>>>(cand_d1, cand_i1, 8 * 2048, 12, idx1, w1);

    // ---- level 1: propagate(xyz1, xyz2, x1, x2) -> inter [8,2048,768] ----
    k_transpose<<<dim3(512 / 32, 512 / 32, 8), dim3(32, 8), 0, stream>>>(
        x2, pts1, 512, 512, 512 * 512, 512 * 512, 512);
    k_transpose<<<dim3(2048 / 32, 256 / 32, 8), dim3(32, 8), 0, stream>>>(
        x1, inter, 256, 2048, 256 * 2048, 2048 * 768, 768);
    k_interp_stats<<<dim3(8, 2048 / 32, 2), 256, 0, stream>>>(
        pts1, idx1, w1, 2048, 512, 512, partials);
    k_finalize<<<1, 256, 0, stream>>>(partials, 1024, (double)8 * 2048 * 512, stats);
    k_interp1_write<<<dim3(8, 2048), 256, 0, stream>>>(pts1, idx1, w1, stats, inter);

    // ---- level 2: propagate(xyz0, xyz1, x0, inter^T) -> out [8,896,8192] ----
    k_interp_stats<<<dim3(8, 8192 / 32, 3), 256, 0, stream>>>(
        inter, idx2, w2, 8192, 2048, 768, partials);
    k_finalize<<<1, 256, 0, stream>>>(partials, 6144, (double)8 * 8192 * 768, stats + 2);
    k_interp2_write<<<dim3(8, 256, 12), 256, 0, stream>>>(inter, idx2, w2, stats + 2, out);
    k_copy0<<<(8 * 262144) / 256, 256, 0, stream>>>(x0, out);
}

// Round 5
// 231.662 us; speedup vs baseline: 2.8085x; 1.0455x over previous
//
#include <hip/hip_runtime.h>
#include <cstdint>
#include <math.h>

// ---------------------------------------------------------------------------
// Problem constants (from setup_inputs)
//   B=8
//   level 1: fine xyz1 [8,2048,3], coarse xyz2 [8,512,3], x1 [8,256,2048], x2 [8,512,512]
//   level 2: fine xyz0 [8,8192,3], coarse xyz1 [8,2048,3], x0 [8,128,8192]
//   out [8, 896, 8192] f32
// Structure: read-only stats gather pass (sources L2-resident, XCD-pinned per
// batch via blockIdx.x = batch), then a write pass emits normalized values once.
// kNN reads coarse points via wave-uniform index from a packed float4 array
// (scalar-pipe s_load) -- no LDS staging, no barrier.
// ---------------------------------------------------------------------------

// Pack coarse xyz + squared norm into float4 arrays for both levels.
// Norm form (x*x + y*y) + z*z matches the reference's expanded distance.
__global__ __launch_bounds__(256) void k_prep4(const float* __restrict__ xyz1,
                                               const float* __restrict__ xyz2,
                                               float4* __restrict__ c2,
                                               float4* __restrict__ c1) {
#pragma clang fp contract(off)
    const int i = blockIdx.x * 256 + threadIdx.x;
    const float* src;
    float4* dst;
    if (i < 16384) { src = xyz1 + 3 * (size_t)i; dst = c2 + i; }
    else if (i < 20480) { src = xyz2 + 3 * (size_t)(i - 16384); dst = c1 + (i - 16384); }
    else return;
    const float x = src[0], y = src[1], z = src[2];
    *dst = make_float4(x, y, z, (x * x + y * y) + z * z);
}

// Tiled transpose: in [B, R, C] row-major -> out[b][c][r] with out row stride out_rs.
__global__ __launch_bounds__(256) void k_transpose(const float* __restrict__ in,
                                                   float* __restrict__ out,
                                                   int R, int C,
                                                   long in_bs, long out_bs, int out_rs) {
    __shared__ float tile[32][33];
    const int b = blockIdx.z;
    const int r0 = blockIdx.y * 32;
    const int c0 = blockIdx.x * 32;
    const float* inb = in + (size_t)b * in_bs;
    float* outb = out + (size_t)b * out_bs;
    const int tx = threadIdx.x;   // 0..31
    const int ty = threadIdx.y;   // 0..7
#pragma unroll
    for (int i = 0; i < 32; i += 8) {
        tile[ty + i][tx] = inb[(size_t)(r0 + ty + i) * C + (c0 + tx)];
    }
    __syncthreads();
#pragma unroll
    for (int i = 0; i < 32; i += 8) {
        outb[(size_t)(c0 + ty + i) * out_rs + (r0 + tx)] = tile[tx][ty + i];
    }
}

// Chunked brute-force 3-NN, LDS-free: coarse points read via wave-uniform index
// from packed float4 (xyz, sqnorm). Uniform __any guard skips the top-3 update
// chain wave-wide when no lane improves.
template <int CHUNK>
__global__ __launch_bounds__(256) void k_knn_chunk(const float* __restrict__ fine,
                                                   const float4* __restrict__ coarse4,
                                                   int N, int S,
                                                   float* __restrict__ cand_d,
                                                   int* __restrict__ cand_i) {
#pragma clang fp contract(off)
    const int b = blockIdx.z;
    const int chunk = blockIdx.y;
    const int nch = gridDim.y;
    const int n = blockIdx.x * 256 + threadIdx.x;
    const int s0 = chunk * CHUNK;
    const float4* cb = coarse4 + (size_t)b * S + s0;
    const float* fp = fine + ((size_t)b * N + n) * 3;
    const float px = fp[0], py = fp[1], pz = fp[2];
    const float psq = (px * px + py * py) + pz * pz;
    float d0 = 1e30f, d1 = 1e30f, d2 = 1e30f;
    int i0 = 0, i1 = 0, i2 = 0;
#pragma unroll 4
    for (int s = 0; s < CHUNK; ++s) {
        const float4 c = cb[s];                       // uniform -> s_load_dwordx4
        const float dot = (px * c.x + py * c.y) + pz * c.z;
        const float d = fmaf(-2.0f, dot, psq + c.w);
        if (__any(d < d2)) {
            const bool lt0 = d < d0, lt1 = d < d1, lt2 = d < d2;
            d2 = lt1 ? d1 : (lt2 ? d : d2);
            i2 = lt1 ? i1 : (lt2 ? s : i2);
            d1 = lt0 ? d0 : (lt1 ? d : d1);
            i1 = lt0 ? i0 : (lt1 ? s : i1);
            d0 = lt0 ? d : d0;
            i0 = lt0 ? s : i0;
        }
    }
    const size_t p = (((size_t)b * N + n) * nch + chunk) * 3;
    cand_d[p] = d0; cand_d[p + 1] = d1; cand_d[p + 2] = d2;
    cand_i[p] = s0 + i0; cand_i[p + 1] = s0 + i1; cand_i[p + 2] = s0 + i2;
}

// Merge per-chunk candidates (chunk-major, each chunk sorted ascending) into
// the final top-3 + normalized inverse-distance weights. Strict < keeps the
// earlier (lower-index) candidate on ties, matching top_k tie-breaking.
__global__ __launch_bounds__(256) void k_knn_merge(const float* __restrict__ cand_d,
                                                   const int* __restrict__ cand_i,
                                                   int npts, int ncand,
                                                   int* __restrict__ idx,
                                                   float* __restrict__ wout) {
    const int p = blockIdx.x * 256 + threadIdx.x;
    if (p >= npts) return;
    const float* cd = cand_d + (size_t)p * ncand;
    const int*   ci = cand_i + (size_t)p * ncand;
    float d0 = 1e30f, d1 = 1e30f, d2 = 1e30f;
    int i0 = 0, i1 = 0, i2 = 0;
    for (int k = 0; k < ncand; ++k) {
        const float d = cd[k];
        const int s = ci[k];
        const bool lt0 = d < d0, lt1 = d < d1, lt2 = d < d2;
        d2 = lt1 ? d1 : (lt2 ? d : d2);
        i2 = lt1 ? i1 : (lt2 ? s : i2);
        d1 = lt0 ? d0 : (lt1 ? d : d1);
        i1 = lt0 ? i0 : (lt1 ? s : i1);
        d0 = lt0 ? d : d0;
        i0 = lt0 ? s : i0;
    }
    const float w0 = 1.0f / (d0 + 1e-8f);
    const float w1 = 1.0f / (d1 + 1e-8f);
    const float w2 = 1.0f / (d2 + 1e-8f);
    const float wsum = (w0 + w1) + w2;
    const size_t q = (size_t)p * 3;
    idx[q] = i0; idx[q + 1] = i1; idx[q + 2] = i2;
    wout[q] = w0 / wsum; wout[q + 1] = w1 / wsum; wout[q + 2] = w2 / wsum;
}

// Stats-only gather pass, float4 gathers: grid (x=B, y=N/32, z=C/256).
// Block: 32 fine points x 256 cols (64 float4). One wave per point-slot,
// 8 groups of 4 points. Per-(b,z) working set = S*256*4 B <= 2 MB -> L2.
__global__ __launch_bounds__(256) void k_interp_stats(const float* __restrict__ pts,
                                                      const int* __restrict__ idx,
                                                      const float* __restrict__ w,
                                                      int N, int S, int C,
                                                      double* __restrict__ partials) {
    __shared__ int   si[32][3];
    __shared__ float sw[32][3];
    const int b = blockIdx.x, nb = blockIdx.y, cb = blockIdx.z;
    const int n0 = nb * 32;
    const int tid = threadIdx.x;
    if (tid < 32) {
        size_t p = ((size_t)b * N + n0 + tid) * 3;
        si[tid][0] = idx[p]; si[tid][1] = idx[p + 1]; si[tid][2] = idx[p + 2];
        sw[tid][0] = w[p];   sw[tid][1] = w[p + 1];   sw[tid][2] = w[p + 2];
    }
    __syncthreads();
    const int C4 = C >> 2;
    const float4* pbf = (const float4*)(pts + (size_t)b * S * C) + (cb * 64);
    const int f = tid & 63;     // float4 col
    const int pg = tid >> 6;    // 0..3
    double ls = 0.0, lq = 0.0;
#pragma unroll
    for (int g = 0; g < 8; ++g) {
        const int nl = g * 4 + pg;
        const size_t r0 = (size_t)si[nl][0] * C4;
        const size_t r1 = (size_t)si[nl][1] * C4;
        const size_t r2 = (size_t)si[nl][2] * C4;
        const float w0 = sw[nl][0], w1 = sw[nl][1], w2 = sw[nl][2];
        const float4 a = pbf[r0 + f], c = pbf[r1 + f], e = pbf[r2 + f];
        const float vx = (w0 * a.x + w1 * c.x) + w2 * e.x;
        const float vy = (w0 * a.y + w1 * c.y) + w2 * e.y;
        const float vz = (w0 * a.z + w1 * c.z) + w2 * e.z;
        const float vw = (w0 * a.w + w1 * c.w) + w2 * e.w;
        ls += (double)vx + (double)vy + (double)vz + (double)vw;
        lq += (double)vx * vx + (double)vy * vy + (double)vz * vz + (double)vw * vw;
    }
    __shared__ double sa[256], sb[256];
    sa[tid] = ls; sb[tid] = lq; __syncthreads();
    for (int s = 128; s > 0; s >>= 1) {
        if (tid < s) { sa[tid] += sa[tid + s]; sb[tid] += sb[tid + s]; }
        __syncthreads();
    }
    if (tid == 0) {
        size_t pl = ((size_t)cb * gridDim.x + b) * gridDim.y + nb;
        partials[2 * pl] = sa[0]; partials[2 * pl + 1] = sb[0];
    }
}

// Deterministic single-block reduction of partials -> stats {mean, 1/(std+1e-5)}.
__global__ __launch_bounds__(256) void k_finalize(const double* __restrict__ partials,
                                                  int P, double nelem,
                                                  float* __restrict__ stats) {
    __shared__ double sa[256], sb[256];
    double ls = 0.0, lq = 0.0;
    for (int i = threadIdx.x; i < P; i += 256) { ls += partials[2 * i]; lq += partials[2 * i + 1]; }
    const int t = threadIdx.x;
    sa[t] = ls; sb[t] = lq; __syncthreads();
    for (int s = 128; s > 0; s >>= 1) {
        if (t < s) { sa[t] += sa[t + s]; sb[t] += sb[t + s]; }
        __syncthreads();
    }
    if (t == 0) {
        double sum = sa[0], sq = sb[0];
        double m = sum / nelem;
        double var = (sq - sum * sum / nelem) / (nelem - 1.0);
        double sd = sqrt(var > 0.0 ? var : 0.0);
        stats[0] = (float)m;
        stats[1] = (float)(1.0 / (sd + 1e-5));
    }
}

// Level-1 write pass, float4: grid (x=B, y=N/4). One wave per fine point;
// gather rows of pts1 [8,512,512] as float4, normalize, write inter[b][n][256+c].
__global__ __launch_bounds__(256) void k_interp1_write(const float* __restrict__ pts,
                                                       const int* __restrict__ idx,
                                                       const float* __restrict__ w,
                                                       const float* __restrict__ stats,
                                                       float* __restrict__ inter) {
    const float m = stats[0], rs = stats[1];
    const int b = blockIdx.x;
    const int n0 = blockIdx.y * 4;
    const int tid = threadIdx.x;
    const int pt = tid >> 6, f = tid & 63;
    const size_t p = (size_t)b * 2048 + n0 + pt;
    const int i0 = idx[p * 3], i1 = idx[p * 3 + 1], i2 = idx[p * 3 + 2];
    const float w0 = w[p * 3], w1 = w[p * 3 + 1], w2 = w[p * 3 + 2];
    const float4* pb4 = (const float4*)(pts + (size_t)b * 512 * 512);
    const size_t r0 = (size_t)i0 * 128, r1 = (size_t)i1 * 128, r2 = (size_t)i2 * 128;
    float4* out4 = (float4*)(inter + p * 768 + 256);
#pragma unroll
    for (int k = 0; k < 2; ++k) {
        const int c = f + k * 64;
        const float4 a = pb4[r0 + c], d = pb4[r1 + c], e = pb4[r2 + c];
        float4 v;
        v.x = (((w0 * a.x + w1 * d.x) + w2 * e.x) - m) * rs;
        v.y = (((w0 * a.y + w1 * d.y) + w2 * e.y) - m) * rs;
        v.z = (((w0 * a.z + w1 * d.z) + w2 * e.z) - m) * rs;
        v.w = (((w0 * a.w + w1 * d.w) + w2 * e.w) - m) * rs;
        out4[c] = v;
    }
}

// Level-2 write pass: grid (x=B, y=128 n-tiles, z=12 c-blocks). Gather rows of
// inter [8,2048,768], normalize, write TRANSPOSED into out[b][128+c][n] via a
// 64(n) x 64(c) LDS tile; stores are single 256 B runs along n.
__global__ __launch_bounds__(256) void k_interp2_write(const float* __restrict__ pts,
                                                       const int* __restrict__ idx,
                                                       const float* __restrict__ w,
                                                       const float* __restrict__ stats,
                                                       float* __restrict__ out) {
    __shared__ float tile[64][65];
    __shared__ int   si[64][3];
    __shared__ float sw[64][3];
    const float m = stats[0], rs = stats[1];
    const int b = blockIdx.x, nt = blockIdx.y, cc = blockIdx.z;
    const int n0 = nt * 64, c0 = cc * 64;
    const int tid = threadIdx.x;
    if (tid < 64) {
        size_t p = ((size_t)b * 8192 + n0 + tid) * 3;
        si[tid][0] = idx[p]; si[tid][1] = idx[p + 1]; si[tid][2] = idx[p + 2];
        sw[tid][0] = w[p];   sw[tid][1] = w[p + 1];   sw[tid][2] = w[p + 2];
    }
    __syncthreads();
    const float* pb = pts + (size_t)b * 2048 * 768 + c0;
    const int cl = tid & 63;
    const int pg = tid >> 6;   // 0..3
#pragma unroll
    for (int pass = 0; pass < 16; ++pass) {
        const int nl = pass * 4 + pg;
        const float v = (sw[nl][0] * pb[(size_t)si[nl][0] * 768 + cl]
                       + sw[nl][1] * pb[(size_t)si[nl][1] * 768 + cl])
                       + sw[nl][2] * pb[(size_t)si[nl][2] * 768 + cl];
        tile[nl][cl] = (v - m) * rs;
    }
    __syncthreads();
    float* ob = out + (size_t)b * 896 * 8192 + (size_t)(128 + c0) * 8192 + n0;
    const int tn = tid & 63, tc0 = tid >> 6;  // 0..3
#pragma unroll
    for (int pass = 0; pass < 16; ++pass) {
        const int tc = pass * 4 + tc0;
        ob[(size_t)tc * 8192 + tn] = tile[tn][tc];
    }
}

// Copy x0 [8,128,8192] into out[:, 0:128, :] (float4).
__global__ __launch_bounds__(256) void k_copy0(const float* __restrict__ x0,
                                               float* __restrict__ out) {
    const size_t i = (size_t)blockIdx.x * 256 + threadIdx.x;   // < 8*262144
    const size_t b = i >> 18;                                  // 262144 = 2^18
    const size_t off = i & (((size_t)1 << 18) - 1);
    const float4* src = (const float4*)(x0 + b * (size_t)128 * 8192);
    float4* dst = (float4*)(out + b * (size_t)896 * 8192);
    dst[off] = src[off];
}

extern "C" void kernel_launch(void* const* d_in, const int* in_sizes, int n_in,
                              void* d_out, int out_size, void* d_ws, size_t ws_size,
                              hipStream_t stream) {
    const float* xyz0 = (const float*)d_in[0];
    const float* xyz1 = (const float*)d_in[1];
    const float* xyz2 = (const float*)d_in[2];
    const float* x0   = (const float*)d_in[3];
    const float* x1   = (const float*)d_in[4];
    const float* x2   = (const float*)d_in[5];
    float* out = (float*)d_out;
    char* ws = (char*)d_ws;

    size_t off = 0;
    auto alloc = [&](size_t bytes) {
        size_t o = off;
        off = (off + bytes + 255) & ~(size_t)255;
        return o;
    };
    float*  stats    = (float*)(ws + alloc(4 * sizeof(float)));
    double* partials = (double*)(ws + alloc((size_t)6144 * 2 * sizeof(double)));
    int*    idx1     = (int*)(ws + alloc((size_t)8 * 2048 * 3 * 4));
    float*  w1       = (float*)(ws + alloc((size_t)8 * 2048 * 3 * 4));
    int*    idx2     = (int*)(ws + alloc((size_t)8 * 8192 * 3 * 4));
    float*  w2       = (float*)(ws + alloc((size_t)8 * 8192 * 3 * 4));
    float4* c4_2     = (float4*)(ws + alloc((size_t)16384 * 16));         // xyz1 packed
    float4* c4_1     = (float4*)(ws + alloc((size_t)4096 * 16));          // xyz2 packed
    float*  pts1     = (float*)(ws + alloc((size_t)8 * 512 * 512 * 4));   // x2^T  [8,512,512]
    float*  inter    = (float*)(ws + alloc((size_t)8 * 2048 * 768 * 4));  // level-1 out, [8,2048,768]

    // knn candidate scratch overlaps pts1/inter (knn runs before the transposes).
    float* cand_d2 = inter;                                   // 65536*24 f32 = 6.3 MB
    int*   cand_i2 = (int*)(inter + (size_t)65536 * 24);      // 6.3 MB (inter is 50 MB)
    float* cand_d1 = pts1;                                    // 16384*24 f32 = 1.6 MB
    int*   cand_i1 = (int*)(pts1 + (size_t)16384 * 24);       // 1.6 MB (pts1 is 8.4 MB)

    // ---- pack coarse points, then kNN for both levels (scratch still free) ----
    k_prep4<<<80, 256, 0, stream>>>(xyz1, xyz2, c4_2, c4_1);
    k_knn_chunk<256><<<dim3(8192 / 256, 8, 8), 256, 0, stream>>>(
        xyz0, c4_2, 8192, 2048, cand_d2, cand_i2);
    k_knn_merge<<<(8 * 8192) / 256, 256, 0, stream>>>(cand_d2, cand_i2, 8 * 8192, 24, idx2, w2);
    k_knn_chunk<64><<<dim3(2048 / 256, 8, 8), 256, 0, stream>>>(
        xyz1, c4_1, 2048, 512, cand_d1, cand_i1);
    k_knn_merge<<<(8 * 2048) / 256, 256, 0, stream>>>(cand_d1, cand_i1, 8 * 2048, 24, idx1, w1);

    // ---- level 1: propagate(xyz1, xyz2, x1, x2) -> inter [8,2048,768] ----
    k_transpose<<<dim3(512 / 32, 512 / 32, 8), dim3(32, 8), 0, stream>>>(
        x2, pts1, 512, 512, 512 * 512, 512 * 512, 512);
    k_transpose<<<dim3(2048 / 32, 256 / 32, 8), dim3(32, 8), 0, stream>>>(
        x1, inter, 256, 2048, 256 * 2048, 2048 * 768, 768);
    k_interp_stats<<<dim3(8, 2048 / 32, 2), 256, 0, stream>>>(
        pts1, idx1, w1, 2048, 512, 512, partials);
    k_finalize<<<1, 256, 0, stream>>>(partials, 1024, (double)8 * 2048 * 512, stats);
    k_interp1_write<<<dim3(8, 512), 256, 0, stream>>>(pts1, idx1, w1, stats, inter);

    // ---- level 2: propagate(xyz0, xyz1, x0, inter^T) -> out [8,896,8192] ----
    k_interp_stats<<<dim3(8, 8192 / 32, 3), 256, 0, stream>>>(
        inter, idx2, w2, 8192, 2048, 768, partials);
    k_finalize<<<1, 256, 0, stream>>>(partials, 6144, (double)8 * 8192 * 768, stats + 2);
    k_interp2_write<<<dim3(8, 128, 12), 256, 0, stream>>>(inter, idx2, w2, stats + 2, out);
    k_copy0<<<(8 * 262144) / 256, 256, 0, stream>>>(x0, out);
}

// Round 6
// 198.535 us; speedup vs baseline: 3.2771x; 1.1669x over previous
//
#include <hip/hip_runtime.h>
#include <cstdint>
#include <math.h>

// ---------------------------------------------------------------------------
// Problem constants
//   B=8
//   level 1: fine xyz1 [8,2048,3], coarse xyz2 [8,512,3], x1 [8,256,2048], x2 [8,512,512]
//   level 2: fine xyz0 [8,8192,3], coarse xyz1 [8,2048,3], x0 [8,128,8192]
//   out [8, 896, 8192] f32
// 9-launch schedule:
//   L1 k_setup   : prep4 | transpose x2->pts1 | transpose x1->inter | copy0
//   L2 k_knn_all : level-2 chunks (512x4) | level-1 chunks (128x4)
//   L3 k_merge   : both levels, ncand=12
//   L4 stats1  L5 fin1  L6 write1  L7 stats2  L8 fin2  L9 write2
// ---------------------------------------------------------------------------

__device__ __forceinline__ void dev_transpose(const float* __restrict__ in,
                                              float* __restrict__ out,
                                              int C, long in_bs, long out_bs, int out_rs,
                                              int b, int rt, int ct, int tid) {
    __shared__ float tile[32][33];
    const int r0 = rt * 32, c0 = ct * 32;
    const float* inb = in + (size_t)b * in_bs;
    float* outb = out + (size_t)b * out_bs;
    const int tx = tid & 31, ty = tid >> 5;   // 32 x 8
#pragma unroll
    for (int i = 0; i < 32; i += 8) {
        tile[ty + i][tx] = inb[(size_t)(r0 + ty + i) * C + (c0 + tx)];
    }
    __syncthreads();
#pragma unroll
    for (int i = 0; i < 32; i += 8) {
        outb[(size_t)(c0 + ty + i) * out_rs + (r0 + tx)] = tile[tx][ty + i];
    }
}

// L1: fused prologue. Blocks: [0,8192) copy0, [8192,12288) transB,
// [12288,14336) transA, [14336,14416) prep4.
__global__ __launch_bounds__(256) void k_setup(const float* __restrict__ xyz1,
                                               const float* __restrict__ xyz2,
                                               const float* __restrict__ x0,
                                               const float* __restrict__ x1,
                                               const float* __restrict__ x2,
                                               float4* __restrict__ c4_2,
                                               float4* __restrict__ c4_1,
                                               float* __restrict__ pts1,
                                               float* __restrict__ inter,
                                               float* __restrict__ out) {
#pragma clang fp contract(off)
    const int id = blockIdx.x;
    const int tid = threadIdx.x;
    if (id < 8192) {                       // copy0: x0 -> out[:,0:128,:]
        const size_t i = (size_t)id * 256 + tid;
        const size_t b = i >> 18;
        const size_t off = i & (((size_t)1 << 18) - 1);
        const float4* src = (const float4*)(x0 + b * (size_t)128 * 8192);
        float4* dst = (float4*)(out + b * (size_t)896 * 8192);
        dst[off] = src[off];
    } else if (id < 12288) {               // transB: x1 [8,256,2048] -> inter[b][c][r], rs=768
        const int t = id - 8192;
        const int ct = t & 63, rt = (t >> 6) & 7, b = t >> 9;
        dev_transpose(x1, inter, 2048, 256 * 2048, (long)2048 * 768, 768, b, rt, ct, tid);
    } else if (id < 14336) {               // transA: x2 [8,512,512] -> pts1, rs=512
        const int t = id - 12288;
        const int ct = t & 15, rt = (t >> 4) & 15, b = t >> 8;
        dev_transpose(x2, pts1, 512, 512 * 512, 512 * 512, 512, b, rt, ct, tid);
    } else {                               // prep4: pack coarse xyz + sqnorm
        const int i = (id - 14336) * 256 + tid;
        const float* src;
        float4* dst;
        if (i < 16384) { src = xyz1 + 3 * (size_t)i; dst = c4_2 + i; }
        else if (i < 20480) { src = xyz2 + 3 * (size_t)(i - 16384); dst = c4_1 + (i - 16384); }
        else return;
        const float x = src[0], y = src[1], z = src[2];
        *dst = make_float4(x, y, z, (x * x + y * y) + z * z);
    }
}

// Chunked 3-NN scan over CHUNK coarse points; coarse read via wave-uniform
// index (s_load). Distance form bit-matches reference's expanded form.
template <int CHUNK>
__device__ __forceinline__ void dev_knn_scan(const float* __restrict__ fine,
                                             const float4* __restrict__ coarse4,
                                             int N, int S, int nch,
                                             int b, int nb, int chunk, int tid,
                                             float* __restrict__ cand_d,
                                             int* __restrict__ cand_i) {
#pragma clang fp contract(off)
    const int n = nb * 256 + tid;
    const int s0 = chunk * CHUNK;
    const float4* cb = coarse4 + (size_t)b * S + s0;
    const float* fp = fine + ((size_t)b * N + n) * 3;
    const float px = fp[0], py = fp[1], pz = fp[2];
    const float psq = (px * px + py * py) + pz * pz;
    float d0 = 1e30f, d1 = 1e30f, d2 = 1e30f;
    int i0 = 0, i1 = 0, i2 = 0;
#pragma unroll 4
    for (int s = 0; s < CHUNK; ++s) {
        const float4 c = cb[s];
        const float dot = (px * c.x + py * c.y) + pz * c.z;
        const float d = fmaf(-2.0f, dot, psq + c.w);
        if (__any(d < d2)) {
            const bool lt0 = d < d0, lt1 = d < d1, lt2 = d < d2;
            d2 = lt1 ? d1 : (lt2 ? d : d2);
            i2 = lt1 ? i1 : (lt2 ? s : i2);
            d1 = lt0 ? d0 : (lt1 ? d : d1);
            i1 = lt0 ? i0 : (lt1 ? s : i1);
            d0 = lt0 ? d : d0;
            i0 = lt0 ? s : i0;
        }
    }
    const size_t p = (((size_t)b * N + n) * nch + chunk) * 3;
    cand_d[p] = d0; cand_d[p + 1] = d1; cand_d[p + 2] = d2;
    cand_i[p] = s0 + i0; cand_i[p + 1] = s0 + i1; cand_i[p + 2] = s0 + i2;
}

// L2: both kNN levels in one launch.
// Blocks [0,1024): level 2 (N=8192, S=2048, CHUNK=512, nch=4):
//   nb = id&31, chunk = (id>>5)&3, b = id>>7.
// Blocks [1024,1280): level 1 (N=2048, S=512, CHUNK=128, nch=4):
//   nb = id&7, chunk = (id>>3)&3, b = id>>5.
__global__ __launch_bounds__(256) void k_knn_all(const float* __restrict__ xyz0,
                                                 const float4* __restrict__ c4_2,
                                                 const float* __restrict__ xyz1,
                                                 const float4* __restrict__ c4_1,
                                                 float* __restrict__ cand_d2,
                                                 int* __restrict__ cand_i2,
                                                 float* __restrict__ cand_d1,
                                                 int* __restrict__ cand_i1) {
    const int id = blockIdx.x;
    const int tid = threadIdx.x;
    if (id < 1024) {
        dev_knn_scan<512>(xyz0, c4_2, 8192, 2048, 4,
                          id >> 7, id & 31, (id >> 5) & 3, tid, cand_d2, cand_i2);
    } else {
        const int t = id - 1024;
        dev_knn_scan<128>(xyz1, c4_1, 2048, 512, 4,
                          t >> 5, t & 7, (t >> 3) & 3, tid, cand_d1, cand_i1);
    }
}

// L3: merge candidates for both levels (ncand=12 each). Strict < keeps the
// earlier (lower-index) candidate on ties, matching top_k tie-breaking.
__global__ __launch_bounds__(256) void k_merge(const float* __restrict__ cand_d2,
                                               const int* __restrict__ cand_i2,
                                               const float* __restrict__ cand_d1,
                                               const int* __restrict__ cand_i1,
                                               int* __restrict__ idx2,
                                               float* __restrict__ w2,
                                               int* __restrict__ idx1,
                                               float* __restrict__ w1) {
    int p = blockIdx.x * 256 + threadIdx.x;
    const float* cd; const int* ci; int* idx; float* wout;
    if (p < 65536) { cd = cand_d2; ci = cand_i2; idx = idx2; wout = w2; }
    else { p -= 65536; cd = cand_d1; ci = cand_i1; idx = idx1; wout = w1; }
    cd += (size_t)p * 12; ci += (size_t)p * 12;
    float d0 = 1e30f, d1 = 1e30f, d2 = 1e30f;
    int i0 = 0, i1 = 0, i2 = 0;
#pragma unroll
    for (int k = 0; k < 12; ++k) {
        const float d = cd[k];
        const int s = ci[k];
        const bool lt0 = d < d0, lt1 = d < d1, lt2 = d < d2;
        d2 = lt1 ? d1 : (lt2 ? d : d2);
        i2 = lt1 ? i1 : (lt2 ? s : i2);
        d1 = lt0 ? d0 : (lt1 ? d : d1);
        i1 = lt0 ? i0 : (lt1 ? s : i1);
        d0 = lt0 ? d : d0;
        i0 = lt0 ? s : i0;
    }
    const float w0 = 1.0f / (d0 + 1e-8f);
    const float w1_ = 1.0f / (d1 + 1e-8f);
    const float w2_ = 1.0f / (d2 + 1e-8f);
    const float wsum = (w0 + w1_) + w2_;
    const size_t q = (size_t)p * 3;
    idx[q] = i0; idx[q + 1] = i1; idx[q + 2] = i2;
    wout[q] = w0 / wsum; wout[q + 1] = w1_ / wsum; wout[q + 2] = w2_ / wsum;
}

// Stats-only gather pass, float4 gathers: grid (x=B, y=N/32, z=C/256).
__global__ __launch_bounds__(256) void k_interp_stats(const float* __restrict__ pts,
                                                      const int* __restrict__ idx,
                                                      const float* __restrict__ w,
                                                      int N, int S, int C,
                                                      double* __restrict__ partials) {
    __shared__ int   si[32][3];
    __shared__ float sw[32][3];
    const int b = blockIdx.x, nb = blockIdx.y, cb = blockIdx.z;
    const int n0 = nb * 32;
    const int tid = threadIdx.x;
    if (tid < 32) {
        size_t p = ((size_t)b * N + n0 + tid) * 3;
        si[tid][0] = idx[p]; si[tid][1] = idx[p + 1]; si[tid][2] = idx[p + 2];
        sw[tid][0] = w[p];   sw[tid][1] = w[p + 1];   sw[tid][2] = w[p + 2];
    }
    __syncthreads();
    const int C4 = C >> 2;
    const float4* pbf = (const float4*)(pts + (size_t)b * S * C) + (cb * 64);
    const int f = tid & 63;
    const int pg = tid >> 6;
    double ls = 0.0, lq = 0.0;
#pragma unroll
    for (int g = 0; g < 8; ++g) {
        const int nl = g * 4 + pg;
        const size_t r0 = (size_t)si[nl][0] * C4;
        const size_t r1 = (size_t)si[nl][1] * C4;
        const size_t r2 = (size_t)si[nl][2] * C4;
        const float w0 = sw[nl][0], w1 = sw[nl][1], w2 = sw[nl][2];
        const float4 a = pbf[r0 + f], c = pbf[r1 + f], e = pbf[r2 + f];
        const float vx = (w0 * a.x + w1 * c.x) + w2 * e.x;
        const float vy = (w0 * a.y + w1 * c.y) + w2 * e.y;
        const float vz = (w0 * a.z + w1 * c.z) + w2 * e.z;
        const float vw = (w0 * a.w + w1 * c.w) + w2 * e.w;
        ls += (double)vx + (double)vy + (double)vz + (double)vw;
        lq += (double)vx * vx + (double)vy * vy + (double)vz * vz + (double)vw * vw;
    }
    __shared__ double sa[256], sb[256];
    sa[tid] = ls; sb[tid] = lq; __syncthreads();
    for (int s = 128; s > 0; s >>= 1) {
        if (tid < s) { sa[tid] += sa[tid + s]; sb[tid] += sb[tid + s]; }
        __syncthreads();
    }
    if (tid == 0) {
        size_t pl = ((size_t)cb * gridDim.x + b) * gridDim.y + nb;
        partials[2 * pl] = sa[0]; partials[2 * pl + 1] = sb[0];
    }
}

// Deterministic single-block reduction of partials -> {mean, 1/(std+1e-5)}.
__global__ __launch_bounds__(1024) void k_finalize(const double* __restrict__ partials,
                                                   int P, double nelem,
                                                   float* __restrict__ stats) {
    __shared__ double sa[1024], sb[1024];
    double ls = 0.0, lq = 0.0;
    for (int i = threadIdx.x; i < P; i += 1024) { ls += partials[2 * i]; lq += partials[2 * i + 1]; }
    const int t = threadIdx.x;
    sa[t] = ls; sb[t] = lq; __syncthreads();
    for (int s = 512; s > 0; s >>= 1) {
        if (t < s) { sa[t] += sa[t + s]; sb[t] += sb[t + s]; }
        __syncthreads();
    }
    if (t == 0) {
        double sum = sa[0], sq = sb[0];
        double m = sum / nelem;
        double var = (sq - sum * sum / nelem) / (nelem - 1.0);
        double sd = sqrt(var > 0.0 ? var : 0.0);
        stats[0] = (float)m;
        stats[1] = (float)(1.0 / (sd + 1e-5));
    }
}

// Level-1 write pass, float4: grid (x=B, y=N/4). One wave per fine point.
__global__ __launch_bounds__(256) void k_interp1_write(const float* __restrict__ pts,
                                                       const int* __restrict__ idx,
                                                       const float* __restrict__ w,
                                                       const float* __restrict__ stats,
                                                       float* __restrict__ inter) {
    const float m = stats[0], rs = stats[1];
    const int b = blockIdx.x;
    const int n0 = blockIdx.y * 4;
    const int tid = threadIdx.x;
    const int pt = tid >> 6, f = tid & 63;
    const size_t p = (size_t)b * 2048 + n0 + pt;
    const int i0 = idx[p * 3], i1 = idx[p * 3 + 1], i2 = idx[p * 3 + 2];
    const float w0 = w[p * 3], w1 = w[p * 3 + 1], w2 = w[p * 3 + 2];
    const float4* pb4 = (const float4*)(pts + (size_t)b * 512 * 512);
    const size_t r0 = (size_t)i0 * 128, r1 = (size_t)i1 * 128, r2 = (size_t)i2 * 128;
    float4* out4 = (float4*)(inter + p * 768 + 256);
#pragma unroll
    for (int k = 0; k < 2; ++k) {
        const int c = f + k * 64;
        const float4 a = pb4[r0 + c], d = pb4[r1 + c], e = pb4[r2 + c];
        float4 v;
        v.x = (((w0 * a.x + w1 * d.x) + w2 * e.x) - m) * rs;
        v.y = (((w0 * a.y + w1 * d.y) + w2 * e.y) - m) * rs;
        v.z = (((w0 * a.z + w1 * d.z) + w2 * e.z) - m) * rs;
        v.w = (((w0 * a.w + w1 * d.w) + w2 * e.w) - m) * rs;
        out4[c] = v;
    }
}

// Level-2 write pass: grid (x=B, y=128 n-tiles, z=12 c-blocks). Gather rows of
// inter [8,2048,768], normalize, write TRANSPOSED into out via 64x64 LDS tile.
__global__ __launch_bounds__(256) void k_interp2_write(const float* __restrict__ pts,
                                                       const int* __restrict__ idx,
                                                       const float* __restrict__ w,
                                                       const float* __restrict__ stats,
                                                       float* __restrict__ out) {
    __shared__ float tile[64][65];
    __shared__ int   si[64][3];
    __shared__ float sw[64][3];
    const float m = stats[0], rs = stats[1];
    const int b = blockIdx.x, nt = blockIdx.y, cc = blockIdx.z;
    const int n0 = nt * 64, c0 = cc * 64;
    const int tid = threadIdx.x;
    if (tid < 64) {
        size_t p = ((size_t)b * 8192 + n0 + tid) * 3;
        si[tid][0] = idx[p]; si[tid][1] = idx[p + 1]; si[tid][2] = idx[p + 2];
        sw[tid][0] = w[p];   sw[tid][1] = w[p + 1];   sw[tid][2] = w[p + 2];
    }
    __syncthreads();
    const float* pb = pts + (size_t)b * 2048 * 768 + c0;
    const int cl = tid & 63;
    const int pg = tid >> 6;
#pragma unroll
    for (int pass = 0; pass < 16; ++pass) {
        const int nl = pass * 4 + pg;
        const float v = (sw[nl][0] * pb[(size_t)si[nl][0] * 768 + cl]
                       + sw[nl][1] * pb[(size_t)si[nl][1] * 768 + cl])
                       + sw[nl][2] * pb[(size_t)si[nl][2] * 768 + cl];
        tile[nl][cl] = (v - m) * rs;
    }
    __syncthreads();
    float* ob = out + (size_t)b * 896 * 8192 + (size_t)(128 + c0) * 8192 + n0;
    const int tn = tid & 63, tc0 = tid >> 6;
#pragma unroll
    for (int pass = 0; pass < 16; ++pass) {
        const int tc = pass * 4 + tc0;
        ob[(size_t)tc * 8192 + tn] = tile[tn][tc];
    }
}

extern "C" void kernel_launch(void* const* d_in, const int* in_sizes, int n_in,
                              void* d_out, int out_size, void* d_ws, size_t ws_size,
                              hipStream_t stream) {
    const float* xyz0 = (const float*)d_in[0];
    const float* xyz1 = (const float*)d_in[1];
    const float* xyz2 = (const float*)d_in[2];
    const float* x0   = (const float*)d_in[3];
    const float* x1   = (const float*)d_in[4];
    const float* x2   = (const float*)d_in[5];
    float* out = (float*)d_out;
    char* ws = (char*)d_ws;

    size_t off = 0;
    auto alloc = [&](size_t bytes) {
        size_t o = off;
        off = (off + bytes + 255) & ~(size_t)255;
        return o;
    };
    float*  stats    = (float*)(ws + alloc(4 * sizeof(float)));
    double* partials = (double*)(ws + alloc((size_t)6144 * 2 * sizeof(double)));
    int*    idx1     = (int*)(ws + alloc((size_t)8 * 2048 * 3 * 4));
    float*  w1       = (float*)(ws + alloc((size_t)8 * 2048 * 3 * 4));
    int*    idx2     = (int*)(ws + alloc((size_t)8 * 8192 * 3 * 4));
    float*  w2       = (float*)(ws + alloc((size_t)8 * 8192 * 3 * 4));
    float4* c4_2     = (float4*)(ws + alloc((size_t)16384 * 16));         // xyz1 packed
    float4* c4_1     = (float4*)(ws + alloc((size_t)4096 * 16));          // xyz2 packed
    float*  pts1     = (float*)(ws + alloc((size_t)8 * 512 * 512 * 4));   // x2^T
    float*  inter    = (float*)(ws + alloc((size_t)8 * 2048 * 768 * 4));  // [8,2048,768]
    float*  cand_d2  = (float*)(ws + alloc((size_t)65536 * 12 * 4));
    int*    cand_i2  = (int*)(ws + alloc((size_t)65536 * 12 * 4));
    float*  cand_d1  = (float*)(ws + alloc((size_t)16384 * 12 * 4));
    int*    cand_i1  = (int*)(ws + alloc((size_t)16384 * 12 * 4));

    // L1: prologue (copy0 | transB | transA | prep4)
    k_setup<<<14416, 256, 0, stream>>>(xyz1, xyz2, x0, x1, x2,
                                       c4_2, c4_1, pts1, inter, out);
    // L2: both kNN levels
    k_knn_all<<<1280, 256, 0, stream>>>(xyz0, c4_2, xyz1, c4_1,
                                        cand_d2, cand_i2, cand_d1, cand_i1);
    // L3: both merges
    k_merge<<<(65536 + 16384) / 256, 256, 0, stream>>>(cand_d2, cand_i2, cand_d1, cand_i1,
                                                       idx2, w2, idx1, w1);
    // L4-L6: level 1
    k_interp_stats<<<dim3(8, 2048 / 32, 2), 256, 0, stream>>>(
        pts1, idx1, w1, 2048, 512, 512, partials);
    k_finalize<<<1, 1024, 0, stream>>>(partials, 1024, (double)8 * 2048 * 512, stats);
    k_interp1_write<<<dim3(8, 512), 256, 0, stream>>>(pts1, idx1, w1, stats, inter);
    // L7-L9: level 2
    k_interp_stats<<<dim3(8, 8192 / 32, 3), 256, 0, stream>>>(
        inter, idx2, w2, 8192, 2048, 768, partials);
    k_finalize<<<1, 1024, 0, stream>>>(partials, 6144, (double)8 * 8192 * 768, stats + 2);
    k_interp2_write<<<dim3(8, 128, 12), 256, 0, stream>>>(inter, idx2, w2, stats + 2, out);
}